// Round 4
// baseline (213.977 us; speedup 1.0000x reference)
//
#include <hip/hip_runtime.h>
#include <hip/hip_bf16.h>

typedef __bf16 bf16_t;
typedef __attribute__((ext_vector_type(8))) __bf16 bf16x8;
typedef __attribute__((ext_vector_type(4))) float f32x4;
typedef __attribute__((ext_vector_type(4))) short s16x4;

#define GLDS16(g, l) __builtin_amdgcn_global_load_lds( \
    (const __attribute__((address_space(1))) unsigned int*)(g), \
    (__attribute__((address_space(3))) unsigned int*)(l), 16, 0, 0)

__device__ __forceinline__ float fexp2(float x) {
#if __has_builtin(__builtin_amdgcn_exp2f)
  return __builtin_amdgcn_exp2f(x);
#else
  return exp2f(x);
#endif
}

// Q pre-scale: 1/sqrt(32) * log2(e) folded into QKV-GEMM epilogue; attention
// softmax runs in the exp2 domain (raw v_exp_f32, no per-score multiply).
#define QSCALE (0.17677669529663688f * 1.4426950408889634f)

// ---------------------------------------------------------------------------
// Kernel 1: convert Wq/Wk/Wv/Wp (f32 [256k][256n]) -> bf16 transposed [n][k]
// ---------------------------------------------------------------------------
__global__ __launch_bounds__(256) void wtr_kernel(
    const float* __restrict__ Wq, const float* __restrict__ Wk,
    const float* __restrict__ Wv, const float* __restrict__ Wp,
    bf16_t* __restrict__ Wt)
{
  const int idx = blockIdx.x * 256 + threadIdx.x;   // 0 .. 262143
  const int mat = idx >> 16;
  const int e   = idx & 65535;
  const int k   = e >> 8;
  const int n   = e & 255;
  const float* W = (mat == 0) ? Wq : (mat == 1) ? Wk : (mat == 2) ? Wv : Wp;
  Wt[(size_t)mat * 65536 + n * 256 + k] = (bf16_t)W[e];  // e == k*256+n
}

// ---------------------------------------------------------------------------
// Kernel 2: LayerNorm, f32 -> bf16. One wave per token (256 ch = 64 lanes x4).
// ---------------------------------------------------------------------------
__global__ __launch_bounds__(256) void ln_kernel(
    const float* __restrict__ x, const float* __restrict__ gamma,
    const float* __restrict__ beta, bf16_t* __restrict__ Xln)
{
  const int wave = threadIdx.x >> 6, lane = threadIdx.x & 63;
  const int tok = blockIdx.x * 4 + wave;
  const float4 v = *reinterpret_cast<const float4*>(x + (size_t)tok * 256 + lane * 4);
  float s1 = v.x + v.y + v.z + v.w;
  float s2 = v.x*v.x + v.y*v.y + v.z*v.z + v.w*v.w;
  #pragma unroll
  for (int off = 1; off < 64; off <<= 1) {
    s1 += __shfl_xor(s1, off);
    s2 += __shfl_xor(s2, off);
  }
  const float mean = s1 * (1.0f/256.0f);
  const float var  = s2 * (1.0f/256.0f) - mean*mean;
  const float rstd = rsqrtf(var + 1e-5f);
  const float4 g  = *reinterpret_cast<const float4*>(gamma + lane*4);
  const float4 be = *reinterpret_cast<const float4*>(beta  + lane*4);
  union { bf16_t h4[4]; unsigned long long u; } pk;
  pk.h4[0] = (bf16_t)((v.x-mean)*rstd*g.x + be.x);
  pk.h4[1] = (bf16_t)((v.y-mean)*rstd*g.y + be.y);
  pk.h4[2] = (bf16_t)((v.z-mean)*rstd*g.z + be.z);
  pk.h4[3] = (bf16_t)((v.w-mean)*rstd*g.w + be.w);
  *reinterpret_cast<unsigned long long*>(Xln + (size_t)tok*256 + lane*4) = pk.u;
}

// ---------------------------------------------------------------------------
// Kernel 3/5: bf16 MFMA GEMM, BM=128 BN=128 BK=64, 4 waves (2x2), K=256.
// MODE 0: A=Xln, B selects Wq/Wk/Wv by blockIdx.y; writes Qb (pre-scaled by
//         QSCALE) / Kb (token-major) or Vt (transposed [b][h][d][n]).
// MODE 1: A=Yb, B=Wpt; writes f32 out + bias.
// LDS tiles XOR-swizzled (byte ^= (row&7)<<4) via pre-swizzled global source.
// ---------------------------------------------------------------------------
template<int MODE>
__global__ __launch_bounds__(256) void gemm_kernel(
    const bf16_t* __restrict__ A, const bf16_t* __restrict__ Wt,
    const float* __restrict__ b0, const float* __restrict__ b1,
    const float* __restrict__ b2,
    bf16_t* __restrict__ Qb, bf16_t* __restrict__ Kb, bf16_t* __restrict__ Vt,
    float* __restrict__ Fout)
{
  __shared__ __align__(16) bf16_t As[128*64];
  __shared__ __align__(16) bf16_t Bs[128*64];
  const int tid  = threadIdx.x;
  const int lane = tid & 63, wave = tid >> 6;
  const int lg = lane >> 4, li = lane & 15;
  const int wm = wave >> 1, wn = wave & 1;
  const int mt = blockIdx.x;
  const int nt = blockIdx.y;
  int mat, nbase;
  const bf16_t* Bm;
  if (MODE == 0) { mat = nt >> 1; nbase = (nt & 1) * 128; Bm = Wt + (size_t)mat * 65536; }
  else           { mat = 3;       nbase = nt * 128;       Bm = Wt; }

  f32x4 acc[4][4] = {};

  for (int kt = 0; kt < 4; ++kt) {
    __syncthreads();
    #pragma unroll
    for (int i = 0; i < 4; ++i) {
      const int idx = i*256 + tid;
      const int row = idx >> 3, ck = idx & 7;
      const int cs = ck ^ (row & 7);
      GLDS16(A + (size_t)(mt*128 + row)*256 + kt*64 + cs*8, As + idx*8);
    }
    #pragma unroll
    for (int i = 0; i < 4; ++i) {
      const int idx = i*256 + tid;
      const int row = idx >> 3, ck = idx & 7;
      const int cs = ck ^ (row & 7);
      GLDS16(Bm + (size_t)(nbase + row)*256 + kt*64 + cs*8, Bs + idx*8);
    }
    __syncthreads();
    #pragma unroll
    for (int kk = 0; kk < 2; ++kk) {
      bf16x8 af[4], bfv[4];
      #pragma unroll
      for (int mi = 0; mi < 4; ++mi) {
        const int row = wm*64 + mi*16 + li;
        const int c = (kk*4 + lg) ^ (row & 7);
        af[mi] = *reinterpret_cast<const bf16x8*>(As + row*64 + c*8);
      }
      #pragma unroll
      for (int ni = 0; ni < 4; ++ni) {
        const int row = wn*64 + ni*16 + li;
        const int c = (kk*4 + lg) ^ (row & 7);
        bfv[ni] = *reinterpret_cast<const bf16x8*>(Bs + row*64 + c*8);
      }
      #pragma unroll
      for (int mi = 0; mi < 4; ++mi)
        #pragma unroll
        for (int ni = 0; ni < 4; ++ni)
          acc[mi][ni] = __builtin_amdgcn_mfma_f32_16x16x32_bf16(af[mi], bfv[ni], acc[mi][ni], 0, 0, 0);
    }
  }

  if (MODE == 0) {
    const float* bias = (mat == 0) ? b0 : (mat == 1) ? b1 : b2;
    if (mat < 2) {
      bf16_t* Out = (mat == 0) ? Qb : Kb;
      const float osc = (mat == 0) ? QSCALE : 1.0f;
      #pragma unroll
      for (int mi = 0; mi < 4; ++mi)
        #pragma unroll
        for (int ni = 0; ni < 4; ++ni) {
          const int col = nbase + wn*64 + ni*16 + li;
          const float bb = bias[col];
          #pragma unroll
          for (int r = 0; r < 4; ++r) {
            const int row = mt*128 + wm*64 + mi*16 + lg*4 + r;
            Out[(size_t)row*256 + col] = (bf16_t)((acc[mi][ni][r] + bb) * osc);
          }
        }
    } else {
      // V: write transposed Vt[b][h][d][n], 4 consecutive tokens -> 8B store
      #pragma unroll
      for (int mi = 0; mi < 4; ++mi)
        #pragma unroll
        for (int ni = 0; ni < 4; ++ni) {
          const int col = nbase + wn*64 + ni*16 + li;
          const int hh = col >> 5, dd = col & 31;
          const float bb = bias[col];
          const int row0 = mt*128 + wm*64 + mi*16 + lg*4;
          const int bi = row0 >> 10, nn = row0 & 1023;
          union { bf16_t h4[4]; unsigned long long u; } pk;
          #pragma unroll
          for (int r = 0; r < 4; ++r) pk.h4[r] = (bf16_t)(acc[mi][ni][r] + bb);
          *reinterpret_cast<unsigned long long*>(
              Vt + ((size_t)(bi*8 + hh)*32 + dd)*1024 + nn) = pk.u;
        }
    }
  } else {
    #pragma unroll
    for (int mi = 0; mi < 4; ++mi)
      #pragma unroll
      for (int ni = 0; ni < 4; ++ni) {
        const int col = nbase + wn*64 + ni*16 + li;
        const float bb = b0[col];
        #pragma unroll
        for (int r = 0; r < 4; ++r) {
          const int row = mt*128 + wm*64 + mi*16 + lg*4 + r;
          Fout[(size_t)row*256 + col] = acc[mi][ni][r] + bb;
        }
      }
  }
}

// ---------------------------------------------------------------------------
// Kernel 4: flash attention, all-register (no LDS).
// Block = (b,h, 64 q-rows), 4 waves x 16 q-rows, fully unrolled 16 chunks.
// S^T = mfma_16x16x32(K,Q): lane li owns q=li, scores k=ct*16+lg*4+r.
// PV uses mfma_16x16x16: its B-operand layout (4 consecutive k per lane,
// k=lg*4+j) EXACTLY matches the QK C-layout quads -> P feeds PV directly
// from registers after 4 bf16 casts. A-operand = V^T 8B quads.
// Softmax: defer-max (THR=8), per-lane; l reduced once at the end.
// ---------------------------------------------------------------------------
__global__ __launch_bounds__(256, 4) void attn_kernel(
    const bf16_t* __restrict__ Qb, const bf16_t* __restrict__ Kb,
    const bf16_t* __restrict__ Vt, bf16_t* __restrict__ Yb)
{
  const int tid  = threadIdx.x;
  const int wave = tid >> 6, lane = tid & 63;
  const int lg = lane >> 4, li = lane & 15;
  const int gid = blockIdx.x;
  const int qt = (gid >> 3) & 15;
  const int bh = ((gid >> 7) << 3) | (gid & 7);   // blocks of one bh: same XCD
  const int b  = bh >> 3, hh = bh & 7;
  const int tok0 = b*1024 + qt*64 + wave*16;

  // B-operand: Q^T[d][q], lane holds q=li, d = lg*8..+7 (pre-scaled, exp2 dom)
  const bf16x8 qf = *reinterpret_cast<const bf16x8*>(
      Qb + (size_t)(tok0 + li)*256 + hh*32 + lg*8);

  // per-lane base pointers
  const bf16_t* Kp  = Kb + (size_t)(b*1024 + li)*256 + hh*32 + lg*8; // +k*256
  const bf16_t* Vp0 = Vt + ((size_t)bh*32 + li)*1024 + lg*4;         // d=li
  const bf16_t* Vp1 = Vp0 + 16*1024;                                 // d=li+16

  const f32x4 fz = {0.f, 0.f, 0.f, 0.f};
  f32x4 acc0 = fz, acc1 = fz;        // Y^T: d = lg*4+r (+16), q = li
  float m = 0.f;                     // defer-max running max (log2 domain)
  float lrow = 0.f;                  // per-lane PARTIAL row sum (own 16 ks)

  bf16x8 kf[2][4];
  #pragma unroll
  for (int ct = 0; ct < 4; ++ct)
    kf[0][ct] = *reinterpret_cast<const bf16x8*>(Kp + (size_t)(ct*16)*256);

  #pragma unroll
  for (int mc = 0; mc < 16; ++mc) {
    const int cur = mc & 1, nxt = cur ^ 1;
    // ---- QK^T from resident K frags ----
    f32x4 s[4];
    #pragma unroll
    for (int ct = 0; ct < 4; ++ct)
      s[ct] = __builtin_amdgcn_mfma_f32_16x16x32_bf16(kf[cur][ct], qf, fz, 0, 0, 0);
    // ---- V quads for this chunk (8B each; consumed after softmax) ----
    s16x4 vq0[4], vq1[4];
    #pragma unroll
    for (int ct = 0; ct < 4; ++ct) {
      vq0[ct] = *reinterpret_cast<const s16x4*>(Vp0 + mc*64 + ct*16);
      vq1[ct] = *reinterpret_cast<const s16x4*>(Vp1 + mc*64 + ct*16);
    }
    // ---- K prefetch (next chunk) ----
    if (mc < 15) {
      #pragma unroll
      for (int ct = 0; ct < 4; ++ct)
        kf[nxt][ct] = *reinterpret_cast<const bf16x8*>(
            Kp + (size_t)((mc+1)*64 + ct*16)*256);
    }
    // ---- defer-max softmax (per-lane; cross-lane only on rare bump) ----
    float mx0 = fmaxf(fmaxf(s[0][0], s[0][1]), fmaxf(s[0][2], s[0][3]));
    float mx1 = fmaxf(fmaxf(s[1][0], s[1][1]), fmaxf(s[1][2], s[1][3]));
    float mx2 = fmaxf(fmaxf(s[2][0], s[2][1]), fmaxf(s[2][2], s[2][3]));
    float mx3 = fmaxf(fmaxf(s[3][0], s[3][1]), fmaxf(s[3][2], s[3][3]));
    const float pmax = fmaxf(fmaxf(mx0, mx1), fmaxf(mx2, mx3));
    if (!__all(pmax - m <= 8.0f)) {
      float rmx = pmax;
      rmx = fmaxf(rmx, __shfl_xor(rmx, 16));
      rmx = fmaxf(rmx, __shfl_xor(rmx, 32));
      const float mnew = fmaxf(m, rmx);
      const float sf = fexp2(m - mnew);
      lrow *= sf;
      #pragma unroll
      for (int r = 0; r < 4; ++r) { acc0[r] *= sf; acc1[r] *= sf; }
      m = mnew;
    }
    float psum = 0.f;
    #pragma unroll
    for (int ct = 0; ct < 4; ++ct) {
      #pragma unroll
      for (int r = 0; r < 4; ++r)
        s[ct][r] = fexp2(s[ct][r] - m);
      psum += (s[ct][0] + s[ct][1]) + (s[ct][2] + s[ct][3]);
    }
    lrow += psum;
    // ---- pack score quads to bf16 and PV via 16x16x16 MFMA (no LDS) ----
    #pragma unroll
    for (int ct = 0; ct < 4; ++ct) {
      union { bf16_t h4[4]; s16x4 v; } pk;
      #pragma unroll
      for (int r = 0; r < 4; ++r) pk.h4[r] = (bf16_t)s[ct][r];
      acc0 = __builtin_amdgcn_mfma_f32_16x16x16bf16_1k(vq0[ct], pk.v, acc0, 0, 0, 0);
      acc1 = __builtin_amdgcn_mfma_f32_16x16x16bf16_1k(vq1[ct], pk.v, acc1, 0, 0, 0);
    }
  }

  // ---- single end-of-loop l reduction across the 4 lg lanes ----
  float lsum = lrow;
  lsum += __shfl_xor(lsum, 16);
  lsum += __shfl_xor(lsum, 32);
  const float inv = 1.0f / lsum;
  union { bf16_t h4[4]; unsigned long long u; } o0, o1;
  #pragma unroll
  for (int r = 0; r < 4; ++r) {
    o0.h4[r] = (bf16_t)(acc0[r]*inv);
    o1.h4[r] = (bf16_t)(acc1[r]*inv);
  }
  bf16_t* yp = Yb + (size_t)(tok0 + li)*256 + hh*32;
  *reinterpret_cast<unsigned long long*>(yp + lg*4)      = o0.u;
  *reinterpret_cast<unsigned long long*>(yp + 16 + lg*4) = o1.u;
}

// ---------------------------------------------------------------------------
extern "C" void kernel_launch(void* const* d_in, const int* in_sizes, int n_in,
                              void* d_out, int out_size, void* d_ws, size_t ws_size,
                              hipStream_t stream) {
  const float* x     = (const float*)d_in[0];
  const float* gamma = (const float*)d_in[1];
  const float* beta  = (const float*)d_in[2];
  const float* Wq    = (const float*)d_in[3];
  const float* bq    = (const float*)d_in[4];
  const float* Wk    = (const float*)d_in[5];
  const float* bk    = (const float*)d_in[6];
  const float* Wv    = (const float*)d_in[7];
  const float* bv    = (const float*)d_in[8];
  const float* Wp    = (const float*)d_in[9];
  const float* bp    = (const float*)d_in[10];
  float* out = (float*)d_out;

  char* ws = (char*)d_ws;
  bf16_t* Wt  = (bf16_t*)(ws);              // 4 * 65536 bf16 = 512 KB
  bf16_t* Xln = (bf16_t*)(ws + 524288);     // 16384*256 bf16 = 8 MB
  bf16_t* Qb  = (bf16_t*)(ws + 8912896);    // 8 MB
  bf16_t* Kb  = (bf16_t*)(ws + 17301504);   // 8 MB
  bf16_t* Vt  = (bf16_t*)(ws + 25690112);   // 8 MB  (total 32.5 MB)
  bf16_t* Yb  = Xln;                        // alias: Xln dead after QKV GEMM

  wtr_kernel<<<1024, 256, 0, stream>>>(Wq, Wk, Wv, Wp, Wt);
  ln_kernel<<<4096, 256, 0, stream>>>(x, gamma, beta, Xln);
  gemm_kernel<0><<<dim3(128, 6), 256, 0, stream>>>(
      Xln, Wt, bq, bk, bv, Qb, Kb, Vt, nullptr);
  attn_kernel<<<2048, 256, 0, stream>>>(Qb, Kb, Vt, Yb);
  gemm_kernel<1><<<dim3(128, 2), 256, 0, stream>>>(
      Yb, Wt + 3*65536, bp, nullptr, nullptr, nullptr, nullptr, nullptr, out);
}

// Round 5
// 81.113 us; speedup vs baseline: 2.6380x; 2.6380x over previous
//
#include <hip/hip_runtime.h>
#include <hip/hip_bf16.h>

typedef __bf16 bf16_t;
typedef __attribute__((ext_vector_type(8))) __bf16 bf16x8;
typedef __attribute__((ext_vector_type(4))) float f32x4;
typedef __attribute__((ext_vector_type(4))) short s16x4;

#define GLDS16(g, l) __builtin_amdgcn_global_load_lds( \
    (const __attribute__((address_space(1))) unsigned int*)(g), \
    (__attribute__((address_space(3))) unsigned int*)(l), 16, 0, 0)

__device__ __forceinline__ float fexp2(float x) {
#if __has_builtin(__builtin_amdgcn_exp2f)
  return __builtin_amdgcn_exp2f(x);
#else
  return exp2f(x);
#endif
}

// Q pre-scale: 1/sqrt(32) * log2(e) folded into QKV-GEMM epilogue; attention
// softmax runs in the exp2 domain (raw v_exp_f32, no per-score multiply).
#define QSCALE (0.17677669529663688f * 1.4426950408889634f)

// ---------------------------------------------------------------------------
// Kernel 1: convert Wq/Wk/Wv/Wp (f32 [256k][256n]) -> bf16 transposed [n][k]
// ---------------------------------------------------------------------------
__global__ __launch_bounds__(256) void wtr_kernel(
    const float* __restrict__ Wq, const float* __restrict__ Wk,
    const float* __restrict__ Wv, const float* __restrict__ Wp,
    bf16_t* __restrict__ Wt)
{
  const int idx = blockIdx.x * 256 + threadIdx.x;   // 0 .. 262143
  const int mat = idx >> 16;
  const int e   = idx & 65535;
  const int k   = e >> 8;
  const int n   = e & 255;
  const float* W = (mat == 0) ? Wq : (mat == 1) ? Wk : (mat == 2) ? Wv : Wp;
  Wt[(size_t)mat * 65536 + n * 256 + k] = (bf16_t)W[e];  // e == k*256+n
}

// ---------------------------------------------------------------------------
// Kernel 2: LayerNorm, f32 -> bf16. One wave per token (256 ch = 64 lanes x4).
// ---------------------------------------------------------------------------
__global__ __launch_bounds__(256) void ln_kernel(
    const float* __restrict__ x, const float* __restrict__ gamma,
    const float* __restrict__ beta, bf16_t* __restrict__ Xln)
{
  const int wave = threadIdx.x >> 6, lane = threadIdx.x & 63;
  const int tok = blockIdx.x * 4 + wave;
  const float4 v = *reinterpret_cast<const float4*>(x + (size_t)tok * 256 + lane * 4);
  float s1 = v.x + v.y + v.z + v.w;
  float s2 = v.x*v.x + v.y*v.y + v.z*v.z + v.w*v.w;
  #pragma unroll
  for (int off = 1; off < 64; off <<= 1) {
    s1 += __shfl_xor(s1, off);
    s2 += __shfl_xor(s2, off);
  }
  const float mean = s1 * (1.0f/256.0f);
  const float var  = s2 * (1.0f/256.0f) - mean*mean;
  const float rstd = rsqrtf(var + 1e-5f);
  const float4 g  = *reinterpret_cast<const float4*>(gamma + lane*4);
  const float4 be = *reinterpret_cast<const float4*>(beta  + lane*4);
  union { bf16_t h4[4]; unsigned long long u; } pk;
  pk.h4[0] = (bf16_t)((v.x-mean)*rstd*g.x + be.x);
  pk.h4[1] = (bf16_t)((v.y-mean)*rstd*g.y + be.y);
  pk.h4[2] = (bf16_t)((v.z-mean)*rstd*g.z + be.z);
  pk.h4[3] = (bf16_t)((v.w-mean)*rstd*g.w + be.w);
  *reinterpret_cast<unsigned long long*>(Xln + (size_t)tok*256 + lane*4) = pk.u;
}

// ---------------------------------------------------------------------------
// Kernel 3/5: bf16 MFMA GEMM, BM=128 BN=128 BK=64, 4 waves (2x2), K=256.
// MODE 0: A=Xln, B selects Wq/Wk/Wv by blockIdx.y; writes Qb (pre-scaled by
//         QSCALE) / Kb (token-major) or Vt (transposed [b][h][d][n]).
// MODE 1: A=Yb, B=Wpt; writes f32 out + bias.
// LDS tiles XOR-swizzled (byte ^= (row&7)<<4) via pre-swizzled global source.
// ---------------------------------------------------------------------------
template<int MODE>
__global__ __launch_bounds__(256) void gemm_kernel(
    const bf16_t* __restrict__ A, const bf16_t* __restrict__ Wt,
    const float* __restrict__ b0, const float* __restrict__ b1,
    const float* __restrict__ b2,
    bf16_t* __restrict__ Qb, bf16_t* __restrict__ Kb, bf16_t* __restrict__ Vt,
    float* __restrict__ Fout)
{
  __shared__ __align__(16) bf16_t As[128*64];
  __shared__ __align__(16) bf16_t Bs[128*64];
  const int tid  = threadIdx.x;
  const int lane = tid & 63, wave = tid >> 6;
  const int lg = lane >> 4, li = lane & 15;
  const int wm = wave >> 1, wn = wave & 1;
  const int mt = blockIdx.x;
  const int nt = blockIdx.y;
  int mat, nbase;
  const bf16_t* Bm;
  if (MODE == 0) { mat = nt >> 1; nbase = (nt & 1) * 128; Bm = Wt + (size_t)mat * 65536; }
  else           { mat = 3;       nbase = nt * 128;       Bm = Wt; }

  f32x4 acc[4][4] = {};

  for (int kt = 0; kt < 4; ++kt) {
    __syncthreads();
    #pragma unroll
    for (int i = 0; i < 4; ++i) {
      const int idx = i*256 + tid;
      const int row = idx >> 3, ck = idx & 7;
      const int cs = ck ^ (row & 7);
      GLDS16(A + (size_t)(mt*128 + row)*256 + kt*64 + cs*8, As + idx*8);
    }
    #pragma unroll
    for (int i = 0; i < 4; ++i) {
      const int idx = i*256 + tid;
      const int row = idx >> 3, ck = idx & 7;
      const int cs = ck ^ (row & 7);
      GLDS16(Bm + (size_t)(nbase + row)*256 + kt*64 + cs*8, Bs + idx*8);
    }
    __syncthreads();
    #pragma unroll
    for (int kk = 0; kk < 2; ++kk) {
      bf16x8 af[4], bfv[4];
      #pragma unroll
      for (int mi = 0; mi < 4; ++mi) {
        const int row = wm*64 + mi*16 + li;
        const int c = (kk*4 + lg) ^ (row & 7);
        af[mi] = *reinterpret_cast<const bf16x8*>(As + row*64 + c*8);
      }
      #pragma unroll
      for (int ni = 0; ni < 4; ++ni) {
        const int row = wn*64 + ni*16 + li;
        const int c = (kk*4 + lg) ^ (row & 7);
        bfv[ni] = *reinterpret_cast<const bf16x8*>(Bs + row*64 + c*8);
      }
      #pragma unroll
      for (int mi = 0; mi < 4; ++mi)
        #pragma unroll
        for (int ni = 0; ni < 4; ++ni)
          acc[mi][ni] = __builtin_amdgcn_mfma_f32_16x16x32_bf16(af[mi], bfv[ni], acc[mi][ni], 0, 0, 0);
    }
  }

  if (MODE == 0) {
    const float* bias = (mat == 0) ? b0 : (mat == 1) ? b1 : b2;
    if (mat < 2) {
      bf16_t* Out = (mat == 0) ? Qb : Kb;
      const float osc = (mat == 0) ? QSCALE : 1.0f;
      #pragma unroll
      for (int mi = 0; mi < 4; ++mi)
        #pragma unroll
        for (int ni = 0; ni < 4; ++ni) {
          const int col = nbase + wn*64 + ni*16 + li;
          const float bb = bias[col];
          #pragma unroll
          for (int r = 0; r < 4; ++r) {
            const int row = mt*128 + wm*64 + mi*16 + lg*4 + r;
            Out[(size_t)row*256 + col] = (bf16_t)((acc[mi][ni][r] + bb) * osc);
          }
        }
    } else {
      // V: write transposed Vt[b][h][d][n], 4 consecutive tokens -> 8B store
      #pragma unroll
      for (int mi = 0; mi < 4; ++mi)
        #pragma unroll
        for (int ni = 0; ni < 4; ++ni) {
          const int col = nbase + wn*64 + ni*16 + li;
          const int hh = col >> 5, dd = col & 31;
          const float bb = bias[col];
          const int row0 = mt*128 + wm*64 + mi*16 + lg*4;
          const int bi = row0 >> 10, nn = row0 & 1023;
          union { bf16_t h4[4]; unsigned long long u; } pk;
          #pragma unroll
          for (int r = 0; r < 4; ++r) pk.h4[r] = (bf16_t)(acc[mi][ni][r] + bb);
          *reinterpret_cast<unsigned long long*>(
              Vt + ((size_t)(bi*8 + hh)*32 + dd)*1024 + nn) = pk.u;
        }
    }
  } else {
    #pragma unroll
    for (int mi = 0; mi < 4; ++mi)
      #pragma unroll
      for (int ni = 0; ni < 4; ++ni) {
        const int col = nbase + wn*64 + ni*16 + li;
        const float bb = b0[col];
        #pragma unroll
        for (int r = 0; r < 4; ++r) {
          const int row = mt*128 + wm*64 + mi*16 + lg*4 + r;
          Fout[(size_t)row*256 + col] = acc[mi][ni][r] + bb;
        }
      }
  }
}

// ---------------------------------------------------------------------------
// Kernel 4: flash attention with LDS-staged K/V (shared by 4 waves),
// double-buffered via global_load_lds (one width-16 instr per 4KB tile).
// Block = (b,h, 64 q-rows), 4 waves x 16 q-rows.
// Pipeline per chunk: issue stage(next) -> compute(cur) -> __syncthreads
// (implicit vmcnt(0) drains stage; barrier protects buffer swap).
// K LDS: [tok][dim], 64B rows, slot ^= (tok>>1)&3  (even b128 bank spread)
// V LDS: [d][tok], 128B rows, slot ^= d&7          (even b64 bank spread)
// Both staged linearly with inverse-swizzled global SOURCE (rule 21).
// QK: S^T = mfma16x16x32(K,Q), lane li owns q=li. Softmax per-lane
// (defer-max THR=8). PV: mfma16x16x16, B = P quads direct from QK output.
// ---------------------------------------------------------------------------
__global__ __launch_bounds__(256, 6) void attn_kernel(
    const bf16_t* __restrict__ Qb, const bf16_t* __restrict__ Kb,
    const bf16_t* __restrict__ Vt, bf16_t* __restrict__ Yb)
{
  __shared__ __align__(16) char Ks[2][4096];
  __shared__ __align__(16) char Vs[2][4096];
  const int tid  = threadIdx.x;
  const int wave = tid >> 6, lane = tid & 63;
  const int lg = lane >> 4, li = lane & 15;
  const int gid = blockIdx.x;
  const int qt = (gid >> 3) & 15;
  const int bh = ((gid >> 7) << 3) | (gid & 7);   // blocks of one bh: same XCD
  const int b  = bh >> 3, hh = bh & 7;
  const int tok0 = b*1024 + qt*64 + wave*16;

  // B-operand: Q^T[d][q], lane holds q=li, d = lg*8..+7 (pre-scaled, exp2 dom)
  const bf16x8 qf = *reinterpret_cast<const bf16x8*>(
      Qb + (size_t)(tok0 + li)*256 + hh*32 + lg*8);

  // ---- staging sources (per-thread, inverse-swizzled) ----
  const int kt_ = tid >> 2, ks_ = tid & 3;     // K: thread -> (tok, 16B slot)
  const bf16_t* Ksrc = Kb + (size_t)(b*1024 + kt_)*256 + hh*32
                          + ((ks_ ^ ((kt_ >> 1) & 3)) * 8);
  const int vd_ = tid >> 3, vs_ = tid & 7;     // V: thread -> (d, 16B slot)
  const bf16_t* Vsrc = Vt + ((size_t)bh*32 + vd_)*1024
                          + ((vs_ ^ (vd_ & 7)) * 8);

  // ---- LDS read offsets (swizzled to match) ----
  const int kof = li*64 + ((lg ^ ((li >> 1) & 3)) * 16);   // + ct*1024
  int vof[4];
  #pragma unroll
  for (int ct = 0; ct < 4; ++ct)
    vof[ct] = li*128 + (((ct*2 + (lg >> 1)) ^ (li & 7)) * 16) + (lg & 1)*8;

  const f32x4 fz = {0.f, 0.f, 0.f, 0.f};
  f32x4 acc0 = fz, acc1 = fz;        // Y^T: d = lg*4+r (+16), q = li
  float m = 0.f;                     // defer-max running max (log2 domain)
  float lrow = 0.f;                  // per-lane PARTIAL row sum (own 16 ks)

  GLDS16(Ksrc, &Ks[0][tid*16]);
  GLDS16(Vsrc, &Vs[0][tid*16]);
  __syncthreads();

  #pragma unroll 2
  for (int mc = 0; mc < 16; ++mc) {
    const int cur = mc & 1;
    // ---- issue next-chunk staging (latency hides under compute) ----
    if (mc < 15) {
      GLDS16(Ksrc + (size_t)(mc+1)*16384, &Ks[cur^1][tid*16]);
      GLDS16(Vsrc + (mc+1)*64,            &Vs[cur^1][tid*16]);
    }
    const char* kb = &Ks[cur][0];
    const char* vb = &Vs[cur][0];
    // ---- QK^T from LDS K tile ----
    f32x4 s[4];
    #pragma unroll
    for (int ct = 0; ct < 4; ++ct) {
      const bf16x8 kfrag = *reinterpret_cast<const bf16x8*>(kb + kof + ct*1024);
      s[ct] = __builtin_amdgcn_mfma_f32_16x16x32_bf16(kfrag, qf, fz, 0, 0, 0);
    }
    // ---- V quads from LDS V tile ----
    s16x4 vq0[4], vq1[4];
    #pragma unroll
    for (int ct = 0; ct < 4; ++ct) {
      vq0[ct] = *reinterpret_cast<const s16x4*>(vb + vof[ct]);
      vq1[ct] = *reinterpret_cast<const s16x4*>(vb + vof[ct] + 16*128);
    }
    // ---- defer-max softmax (per-lane; cross-lane only on rare bump) ----
    float mx0 = fmaxf(fmaxf(s[0][0], s[0][1]), fmaxf(s[0][2], s[0][3]));
    float mx1 = fmaxf(fmaxf(s[1][0], s[1][1]), fmaxf(s[1][2], s[1][3]));
    float mx2 = fmaxf(fmaxf(s[2][0], s[2][1]), fmaxf(s[2][2], s[2][3]));
    float mx3 = fmaxf(fmaxf(s[3][0], s[3][1]), fmaxf(s[3][2], s[3][3]));
    const float pmax = fmaxf(fmaxf(mx0, mx1), fmaxf(mx2, mx3));
    if (!__all(pmax - m <= 8.0f)) {
      float rmx = pmax;
      rmx = fmaxf(rmx, __shfl_xor(rmx, 16));
      rmx = fmaxf(rmx, __shfl_xor(rmx, 32));
      const float mnew = fmaxf(m, rmx);
      const float sf = fexp2(m - mnew);
      lrow *= sf;
      #pragma unroll
      for (int r = 0; r < 4; ++r) { acc0[r] *= sf; acc1[r] *= sf; }
      m = mnew;
    }
    float psum = 0.f;
    #pragma unroll
    for (int ct = 0; ct < 4; ++ct) {
      #pragma unroll
      for (int r = 0; r < 4; ++r)
        s[ct][r] = fexp2(s[ct][r] - m);
      psum += (s[ct][0] + s[ct][1]) + (s[ct][2] + s[ct][3]);
    }
    lrow += psum;
    // ---- pack score quads to bf16 and PV via 16x16x16 MFMA ----
    #pragma unroll
    for (int ct = 0; ct < 4; ++ct) {
      union { bf16_t h4[4]; s16x4 v; } pk;
      #pragma unroll
      for (int r = 0; r < 4; ++r) pk.h4[r] = (bf16_t)s[ct][r];
      acc0 = __builtin_amdgcn_mfma_f32_16x16x16bf16_1k(vq0[ct], pk.v, acc0, 0, 0, 0);
      acc1 = __builtin_amdgcn_mfma_f32_16x16x16bf16_1k(vq1[ct], pk.v, acc1, 0, 0, 0);
    }
    // barrier: stage(next) complete (vmcnt0) + all waves done reading cur
    __syncthreads();
  }

  // ---- single end-of-loop l reduction across the 4 lg lanes ----
  float lsum = lrow;
  lsum += __shfl_xor(lsum, 16);
  lsum += __shfl_xor(lsum, 32);
  const float inv = 1.0f / lsum;
  union { bf16_t h4[4]; unsigned long long u; } o0, o1;
  #pragma unroll
  for (int r = 0; r < 4; ++r) {
    o0.h4[r] = (bf16_t)(acc0[r]*inv);
    o1.h4[r] = (bf16_t)(acc1[r]*inv);
  }
  bf16_t* yp = Yb + (size_t)(tok0 + li)*256 + hh*32;
  *reinterpret_cast<unsigned long long*>(yp + lg*4)      = o0.u;
  *reinterpret_cast<unsigned long long*>(yp + 16 + lg*4) = o1.u;
}

// ---------------------------------------------------------------------------
extern "C" void kernel_launch(void* const* d_in, const int* in_sizes, int n_in,
                              void* d_out, int out_size, void* d_ws, size_t ws_size,
                              hipStream_t stream) {
  const float* x     = (const float*)d_in[0];
  const float* gamma = (const float*)d_in[1];
  const float* beta  = (const float*)d_in[2];
  const float* Wq    = (const float*)d_in[3];
  const float* bq    = (const float*)d_in[4];
  const float* Wk    = (const float*)d_in[5];
  const float* bk    = (const float*)d_in[6];
  const float* Wv    = (const float*)d_in[7];
  const float* bv    = (const float*)d_in[8];
  const float* Wp    = (const float*)d_in[9];
  const float* bp    = (const float*)d_in[10];
  float* out = (float*)d_out;

  char* ws = (char*)d_ws;
  bf16_t* Wt  = (bf16_t*)(ws);              // 4 * 65536 bf16 = 512 KB
  bf16_t* Xln = (bf16_t*)(ws + 524288);     // 16384*256 bf16 = 8 MB
  bf16_t* Qb  = (bf16_t*)(ws + 8912896);    // 8 MB
  bf16_t* Kb  = (bf16_t*)(ws + 17301504);   // 8 MB
  bf16_t* Vt  = (bf16_t*)(ws + 25690112);   // 8 MB  (total 32.5 MB)
  bf16_t* Yb  = Xln;                        // alias: Xln dead after QKV GEMM

  wtr_kernel<<<1024, 256, 0, stream>>>(Wq, Wk, Wv, Wp, Wt);
  ln_kernel<<<4096, 256, 0, stream>>>(x, gamma, beta, Xln);
  gemm_kernel<0><<<dim3(128, 6), 256, 0, stream>>>(
      Xln, Wt, bq, bk, bv, Qb, Kb, Vt, nullptr);
  attn_kernel<<<2048, 256, 0, stream>>>(Qb, Kb, Vt, Yb);
  gemm_kernel<1><<<dim3(128, 2), 256, 0, stream>>>(
      Yb, Wt + 3*65536, bp, nullptr, nullptr, nullptr, nullptr, nullptr, out);
}

// Round 6
// 79.423 us; speedup vs baseline: 2.6942x; 1.0213x over previous
//
#include <hip/hip_runtime.h>
#include <hip/hip_bf16.h>

typedef __bf16 bf16_t;
typedef __attribute__((ext_vector_type(8))) __bf16 bf16x8;
typedef __attribute__((ext_vector_type(4))) float f32x4;
typedef __attribute__((ext_vector_type(4))) short s16x4;

#define GLDS16(g, l) __builtin_amdgcn_global_load_lds( \
    (const __attribute__((address_space(1))) unsigned int*)(g), \
    (__attribute__((address_space(3))) unsigned int*)(l), 16, 0, 0)

__device__ __forceinline__ float fexp2(float x) {
#if __has_builtin(__builtin_amdgcn_exp2f)
  return __builtin_amdgcn_exp2f(x);
#else
  return exp2f(x);
#endif
}

// Q pre-scale: 1/sqrt(32) * log2(e) folded into QKV-GEMM epilogue; attention
// softmax runs in the exp2 domain (raw v_exp_f32, no per-score multiply).
#define QSCALE (0.17677669529663688f * 1.4426950408889634f)

// ---------------------------------------------------------------------------
// Kernel 1: convert Wq/Wk/Wv/Wp (f32 [256k][256n]) -> bf16 transposed [n][k]
// ---------------------------------------------------------------------------
__global__ __launch_bounds__(256) void wtr_kernel(
    const float* __restrict__ Wq, const float* __restrict__ Wk,
    const float* __restrict__ Wv, const float* __restrict__ Wp,
    bf16_t* __restrict__ Wt)
{
  const int idx = blockIdx.x * 256 + threadIdx.x;   // 0 .. 262143
  const int mat = idx >> 16;
  const int e   = idx & 65535;
  const int k   = e >> 8;
  const int n   = e & 255;
  const float* W = (mat == 0) ? Wq : (mat == 1) ? Wk : (mat == 2) ? Wv : Wp;
  Wt[(size_t)mat * 65536 + n * 256 + k] = (bf16_t)W[e];  // e == k*256+n
}

// ---------------------------------------------------------------------------
// Kernel 2: LayerNorm, f32 -> bf16. One wave per token (256 ch = 64 lanes x4).
// ---------------------------------------------------------------------------
__global__ __launch_bounds__(256) void ln_kernel(
    const float* __restrict__ x, const float* __restrict__ gamma,
    const float* __restrict__ beta, bf16_t* __restrict__ Xln)
{
  const int wave = threadIdx.x >> 6, lane = threadIdx.x & 63;
  const int tok = blockIdx.x * 4 + wave;
  const float4 v = *reinterpret_cast<const float4*>(x + (size_t)tok * 256 + lane * 4);
  float s1 = v.x + v.y + v.z + v.w;
  float s2 = v.x*v.x + v.y*v.y + v.z*v.z + v.w*v.w;
  #pragma unroll
  for (int off = 1; off < 64; off <<= 1) {
    s1 += __shfl_xor(s1, off);
    s2 += __shfl_xor(s2, off);
  }
  const float mean = s1 * (1.0f/256.0f);
  const float var  = s2 * (1.0f/256.0f) - mean*mean;
  const float rstd = rsqrtf(var + 1e-5f);
  const float4 g  = *reinterpret_cast<const float4*>(gamma + lane*4);
  const float4 be = *reinterpret_cast<const float4*>(beta  + lane*4);
  union { bf16_t h4[4]; unsigned long long u; } pk;
  pk.h4[0] = (bf16_t)((v.x-mean)*rstd*g.x + be.x);
  pk.h4[1] = (bf16_t)((v.y-mean)*rstd*g.y + be.y);
  pk.h4[2] = (bf16_t)((v.z-mean)*rstd*g.z + be.z);
  pk.h4[3] = (bf16_t)((v.w-mean)*rstd*g.w + be.w);
  *reinterpret_cast<unsigned long long*>(Xln + (size_t)tok*256 + lane*4) = pk.u;
}

// ---------------------------------------------------------------------------
// Kernel 3/5: bf16 MFMA GEMM, BM=128 BN=128 BK=64, 4 waves (2x2), K=256.
// MODE 0: A=Xln, B selects Wq/Wk/Wv by blockIdx.y; writes Qb (pre-scaled by
//         QSCALE) / Kb (token-major) or Vt (transposed [b][h][d][n]).
// MODE 1: A=Yb, B=Wpt; writes f32 out + bias.
// LDS tiles XOR-swizzled (byte ^= (row&7)<<4) via pre-swizzled global source.
// ---------------------------------------------------------------------------
template<int MODE>
__global__ __launch_bounds__(256) void gemm_kernel(
    const bf16_t* __restrict__ A, const bf16_t* __restrict__ Wt,
    const float* __restrict__ b0, const float* __restrict__ b1,
    const float* __restrict__ b2,
    bf16_t* __restrict__ Qb, bf16_t* __restrict__ Kb, bf16_t* __restrict__ Vt,
    float* __restrict__ Fout)
{
  __shared__ __align__(16) bf16_t As[128*64];
  __shared__ __align__(16) bf16_t Bs[128*64];
  const int tid  = threadIdx.x;
  const int lane = tid & 63, wave = tid >> 6;
  const int lg = lane >> 4, li = lane & 15;
  const int wm = wave >> 1, wn = wave & 1;
  const int mt = blockIdx.x;
  const int nt = blockIdx.y;
  int mat, nbase;
  const bf16_t* Bm;
  if (MODE == 0) { mat = nt >> 1; nbase = (nt & 1) * 128; Bm = Wt + (size_t)mat * 65536; }
  else           { mat = 3;       nbase = nt * 128;       Bm = Wt; }

  f32x4 acc[4][4] = {};

  for (int kt = 0; kt < 4; ++kt) {
    __syncthreads();
    #pragma unroll
    for (int i = 0; i < 4; ++i) {
      const int idx = i*256 + tid;
      const int row = idx >> 3, ck = idx & 7;
      const int cs = ck ^ (row & 7);
      GLDS16(A + (size_t)(mt*128 + row)*256 + kt*64 + cs*8, As + idx*8);
    }
    #pragma unroll
    for (int i = 0; i < 4; ++i) {
      const int idx = i*256 + tid;
      const int row = idx >> 3, ck = idx & 7;
      const int cs = ck ^ (row & 7);
      GLDS16(Bm + (size_t)(nbase + row)*256 + kt*64 + cs*8, Bs + idx*8);
    }
    __syncthreads();
    #pragma unroll
    for (int kk = 0; kk < 2; ++kk) {
      bf16x8 af[4], bfv[4];
      #pragma unroll
      for (int mi = 0; mi < 4; ++mi) {
        const int row = wm*64 + mi*16 + li;
        const int c = (kk*4 + lg) ^ (row & 7);
        af[mi] = *reinterpret_cast<const bf16x8*>(As + row*64 + c*8);
      }
      #pragma unroll
      for (int ni = 0; ni < 4; ++ni) {
        const int row = wn*64 + ni*16 + li;
        const int c = (kk*4 + lg) ^ (row & 7);
        bfv[ni] = *reinterpret_cast<const bf16x8*>(Bs + row*64 + c*8);
      }
      #pragma unroll
      for (int mi = 0; mi < 4; ++mi)
        #pragma unroll
        for (int ni = 0; ni < 4; ++ni)
          acc[mi][ni] = __builtin_amdgcn_mfma_f32_16x16x32_bf16(af[mi], bfv[ni], acc[mi][ni], 0, 0, 0);
    }
  }

  if (MODE == 0) {
    const float* bias = (mat == 0) ? b0 : (mat == 1) ? b1 : b2;
    if (mat < 2) {
      bf16_t* Out = (mat == 0) ? Qb : Kb;
      const float osc = (mat == 0) ? QSCALE : 1.0f;
      #pragma unroll
      for (int mi = 0; mi < 4; ++mi)
        #pragma unroll
        for (int ni = 0; ni < 4; ++ni) {
          const int col = nbase + wn*64 + ni*16 + li;
          const float bb = bias[col];
          #pragma unroll
          for (int r = 0; r < 4; ++r) {
            const int row = mt*128 + wm*64 + mi*16 + lg*4 + r;
            Out[(size_t)row*256 + col] = (bf16_t)((acc[mi][ni][r] + bb) * osc);
          }
        }
    } else {
      // V: write transposed Vt[b][h][d][n], 4 consecutive tokens -> 8B store
      #pragma unroll
      for (int mi = 0; mi < 4; ++mi)
        #pragma unroll
        for (int ni = 0; ni < 4; ++ni) {
          const int col = nbase + wn*64 + ni*16 + li;
          const int hh = col >> 5, dd = col & 31;
          const float bb = bias[col];
          const int row0 = mt*128 + wm*64 + mi*16 + lg*4;
          const int bi = row0 >> 10, nn = row0 & 1023;
          union { bf16_t h4[4]; unsigned long long u; } pk;
          #pragma unroll
          for (int r = 0; r < 4; ++r) pk.h4[r] = (bf16_t)(acc[mi][ni][r] + bb);
          *reinterpret_cast<unsigned long long*>(
              Vt + ((size_t)(bi*8 + hh)*32 + dd)*1024 + nn) = pk.u;
        }
    }
  } else {
    #pragma unroll
    for (int mi = 0; mi < 4; ++mi)
      #pragma unroll
      for (int ni = 0; ni < 4; ++ni) {
        const int col = nbase + wn*64 + ni*16 + li;
        const float bb = b0[col];
        #pragma unroll
        for (int r = 0; r < 4; ++r) {
          const int row = mt*128 + wm*64 + mi*16 + lg*4 + r;
          Fout[(size_t)row*256 + col] = acc[mi][ni][r] + bb;
        }
      }
  }
}

// ---------------------------------------------------------------------------
// Kernel 4: flash attention, LDS-staged K/V + 32 q-rows per wave.
// Block = (b,h, 128 q-rows), 4 waves x 32 q-rows (2 Q-fragments each).
// Doubling q per wave halves LDS read traffic per FLOP (the round-5
// bottleneck: 4 waves re-reading the whole 8KB K/V tile every chunk).
// K LDS: [tok][dim], 64B rows, slot ^= (tok>>1)&3  (even b128 bank spread)
// V LDS: [d][tok], 128B rows, slot ^= d&7          (even b64 bank spread)
// Staged linearly via global_load_lds w/ inverse-swizzled global source.
// QK: S^T = mfma16x16x32(K,Q) per Q-frag. Softmax per-lane (defer-max
// THR=8). PV: mfma16x16x16, B = P quads direct from QK output registers.
// ---------------------------------------------------------------------------
__global__ __launch_bounds__(256, 4) void attn_kernel(
    const bf16_t* __restrict__ Qb, const bf16_t* __restrict__ Kb,
    const bf16_t* __restrict__ Vt, bf16_t* __restrict__ Yb)
{
  __shared__ __align__(16) char Ks[2][4096];
  __shared__ __align__(16) char Vs[2][4096];
  const int tid  = threadIdx.x;
  const int wave = tid >> 6, lane = tid & 63;
  const int lg = lane >> 4, li = lane & 15;
  const int gid = blockIdx.x;
  const int qt = (gid >> 3) & 7;
  const int bh = ((gid >> 6) << 3) | (gid & 7);   // blocks of one bh: same XCD
  const int b  = bh >> 3, hh = bh & 7;
  const int tok0 = b*1024 + qt*128 + wave*32;

  // B-operand: Q^T[d][q]; lane holds q=li within each 16-row fragment
  const bf16x8 qf0 = *reinterpret_cast<const bf16x8*>(
      Qb + (size_t)(tok0 + li)*256 + hh*32 + lg*8);
  const bf16x8 qf1 = *reinterpret_cast<const bf16x8*>(
      Qb + (size_t)(tok0 + 16 + li)*256 + hh*32 + lg*8);

  // ---- staging sources (per-thread, inverse-swizzled) ----
  const int kt_ = tid >> 2, ks_ = tid & 3;     // K: thread -> (tok, 16B slot)
  const bf16_t* Ksrc = Kb + (size_t)(b*1024 + kt_)*256 + hh*32
                          + ((ks_ ^ ((kt_ >> 1) & 3)) * 8);
  const int vd_ = tid >> 3, vs_ = tid & 7;     // V: thread -> (d, 16B slot)
  const bf16_t* Vsrc = Vt + ((size_t)bh*32 + vd_)*1024
                          + ((vs_ ^ (vd_ & 7)) * 8);

  // ---- LDS read offsets (swizzled to match) ----
  const int kof = li*64 + ((lg ^ ((li >> 1) & 3)) * 16);   // + ct*1024
  int vof[4];
  #pragma unroll
  for (int ct = 0; ct < 4; ++ct)
    vof[ct] = li*128 + (((ct*2 + (lg >> 1)) ^ (li & 7)) * 16) + (lg & 1)*8;

  const f32x4 fz = {0.f, 0.f, 0.f, 0.f};
  f32x4 acc00 = fz, acc01 = fz;      // qf0 rows: d = lg*4+r (+16), q = li
  f32x4 acc10 = fz, acc11 = fz;      // qf1 rows
  float m0 = 0.f, m1 = 0.f;          // defer-max running max (log2 domain)
  float lrow0 = 0.f, lrow1 = 0.f;    // per-lane PARTIAL row sums

  GLDS16(Ksrc, &Ks[0][tid*16]);
  GLDS16(Vsrc, &Vs[0][tid*16]);
  __syncthreads();

  #pragma unroll 2
  for (int mc = 0; mc < 16; ++mc) {
    const int cur = mc & 1;
    // ---- issue next-chunk staging (latency hides under compute) ----
    if (mc < 15) {
      GLDS16(Ksrc + (size_t)(mc+1)*16384, &Ks[cur^1][tid*16]);
      GLDS16(Vsrc + (mc+1)*64,            &Vs[cur^1][tid*16]);
    }
    const char* kb = &Ks[cur][0];
    const char* vb = &Vs[cur][0];
    // ---- QK^T from LDS K tile (one K-frag read feeds both Q-frags) ----
    f32x4 s0[4], s1[4];
    #pragma unroll
    for (int ct = 0; ct < 4; ++ct) {
      const bf16x8 kfrag = *reinterpret_cast<const bf16x8*>(kb + kof + ct*1024);
      s0[ct] = __builtin_amdgcn_mfma_f32_16x16x32_bf16(kfrag, qf0, fz, 0, 0, 0);
      s1[ct] = __builtin_amdgcn_mfma_f32_16x16x32_bf16(kfrag, qf1, fz, 0, 0, 0);
    }
    // ---- V quads from LDS V tile (shared by both Q-frags) ----
    s16x4 vq0[4], vq1[4];
    #pragma unroll
    for (int ct = 0; ct < 4; ++ct) {
      vq0[ct] = *reinterpret_cast<const s16x4*>(vb + vof[ct]);
      vq1[ct] = *reinterpret_cast<const s16x4*>(vb + vof[ct] + 16*128);
    }
    // ---- defer-max softmax, fragment 0 ----
    {
      float mxa = fmaxf(fmaxf(s0[0][0], s0[0][1]), fmaxf(s0[0][2], s0[0][3]));
      float mxb = fmaxf(fmaxf(s0[1][0], s0[1][1]), fmaxf(s0[1][2], s0[1][3]));
      float mxc = fmaxf(fmaxf(s0[2][0], s0[2][1]), fmaxf(s0[2][2], s0[2][3]));
      float mxd = fmaxf(fmaxf(s0[3][0], s0[3][1]), fmaxf(s0[3][2], s0[3][3]));
      const float pmax = fmaxf(fmaxf(mxa, mxb), fmaxf(mxc, mxd));
      if (!__all(pmax - m0 <= 8.0f)) {
        float rmx = pmax;
        rmx = fmaxf(rmx, __shfl_xor(rmx, 16));
        rmx = fmaxf(rmx, __shfl_xor(rmx, 32));
        const float mnew = fmaxf(m0, rmx);
        const float sf = fexp2(m0 - mnew);
        lrow0 *= sf;
        #pragma unroll
        for (int r = 0; r < 4; ++r) { acc00[r] *= sf; acc01[r] *= sf; }
        m0 = mnew;
      }
      float psum = 0.f;
      #pragma unroll
      for (int ct = 0; ct < 4; ++ct) {
        #pragma unroll
        for (int r = 0; r < 4; ++r)
          s0[ct][r] = fexp2(s0[ct][r] - m0);
        psum += (s0[ct][0] + s0[ct][1]) + (s0[ct][2] + s0[ct][3]);
      }
      lrow0 += psum;
    }
    // ---- defer-max softmax, fragment 1 ----
    {
      float mxa = fmaxf(fmaxf(s1[0][0], s1[0][1]), fmaxf(s1[0][2], s1[0][3]));
      float mxb = fmaxf(fmaxf(s1[1][0], s1[1][1]), fmaxf(s1[1][2], s1[1][3]));
      float mxc = fmaxf(fmaxf(s1[2][0], s1[2][1]), fmaxf(s1[2][2], s1[2][3]));
      float mxd = fmaxf(fmaxf(s1[3][0], s1[3][1]), fmaxf(s1[3][2], s1[3][3]));
      const float pmax = fmaxf(fmaxf(mxa, mxb), fmaxf(mxc, mxd));
      if (!__all(pmax - m1 <= 8.0f)) {
        float rmx = pmax;
        rmx = fmaxf(rmx, __shfl_xor(rmx, 16));
        rmx = fmaxf(rmx, __shfl_xor(rmx, 32));
        const float mnew = fmaxf(m1, rmx);
        const float sf = fexp2(m1 - mnew);
        lrow1 *= sf;
        #pragma unroll
        for (int r = 0; r < 4; ++r) { acc10[r] *= sf; acc11[r] *= sf; }
        m1 = mnew;
      }
      float psum = 0.f;
      #pragma unroll
      for (int ct = 0; ct < 4; ++ct) {
        #pragma unroll
        for (int r = 0; r < 4; ++r)
          s1[ct][r] = fexp2(s1[ct][r] - m1);
        psum += (s1[ct][0] + s1[ct][1]) + (s1[ct][2] + s1[ct][3]);
      }
      lrow1 += psum;
    }
    // ---- pack score quads to bf16; PV via 16x16x16 MFMA (shared V) ----
    #pragma unroll
    for (int ct = 0; ct < 4; ++ct) {
      union { bf16_t h4[4]; s16x4 v; } p0, p1;
      #pragma unroll
      for (int r = 0; r < 4; ++r) { p0.h4[r] = (bf16_t)s0[ct][r];
                                    p1.h4[r] = (bf16_t)s1[ct][r]; }
      acc00 = __builtin_amdgcn_mfma_f32_16x16x16bf16_1k(vq0[ct], p0.v, acc00, 0, 0, 0);
      acc01 = __builtin_amdgcn_mfma_f32_16x16x16bf16_1k(vq1[ct], p0.v, acc01, 0, 0, 0);
      acc10 = __builtin_amdgcn_mfma_f32_16x16x16bf16_1k(vq0[ct], p1.v, acc10, 0, 0, 0);
      acc11 = __builtin_amdgcn_mfma_f32_16x16x16bf16_1k(vq1[ct], p1.v, acc11, 0, 0, 0);
    }
    // barrier: stage(next) complete (vmcnt0) + all waves done reading cur
    __syncthreads();
  }

  // ---- end-of-loop l reductions across the 4 lg lanes ----
  float ls0 = lrow0, ls1 = lrow1;
  ls0 += __shfl_xor(ls0, 16); ls0 += __shfl_xor(ls0, 32);
  ls1 += __shfl_xor(ls1, 16); ls1 += __shfl_xor(ls1, 32);
  const float inv0 = 1.0f / ls0, inv1 = 1.0f / ls1;
  union { bf16_t h4[4]; unsigned long long u; } o00, o01, o10, o11;
  #pragma unroll
  for (int r = 0; r < 4; ++r) {
    o00.h4[r] = (bf16_t)(acc00[r]*inv0);
    o01.h4[r] = (bf16_t)(acc01[r]*inv0);
    o10.h4[r] = (bf16_t)(acc10[r]*inv1);
    o11.h4[r] = (bf16_t)(acc11[r]*inv1);
  }
  bf16_t* yp0 = Yb + (size_t)(tok0 + li)*256 + hh*32;
  bf16_t* yp1 = Yb + (size_t)(tok0 + 16 + li)*256 + hh*32;
  *reinterpret_cast<unsigned long long*>(yp0 + lg*4)      = o00.u;
  *reinterpret_cast<unsigned long long*>(yp0 + 16 + lg*4) = o01.u;
  *reinterpret_cast<unsigned long long*>(yp1 + lg*4)      = o10.u;
  *reinterpret_cast<unsigned long long*>(yp1 + 16 + lg*4) = o11.u;
}

// ---------------------------------------------------------------------------
extern "C" void kernel_launch(void* const* d_in, const int* in_sizes, int n_in,
                              void* d_out, int out_size, void* d_ws, size_t ws_size,
                              hipStream_t stream) {
  const float* x     = (const float*)d_in[0];
  const float* gamma = (const float*)d_in[1];
  const float* beta  = (const float*)d_in[2];
  const float* Wq    = (const float*)d_in[3];
  const float* bq    = (const float*)d_in[4];
  const float* Wk    = (const float*)d_in[5];
  const float* bk    = (const float*)d_in[6];
  const float* Wv    = (const float*)d_in[7];
  const float* bv    = (const float*)d_in[8];
  const float* Wp    = (const float*)d_in[9];
  const float* bp    = (const float*)d_in[10];
  float* out = (float*)d_out;

  char* ws = (char*)d_ws;
  bf16_t* Wt  = (bf16_t*)(ws);              // 4 * 65536 bf16 = 512 KB
  bf16_t* Xln = (bf16_t*)(ws + 524288);     // 16384*256 bf16 = 8 MB
  bf16_t* Qb  = (bf16_t*)(ws + 8912896);    // 8 MB
  bf16_t* Kb  = (bf16_t*)(ws + 17301504);   // 8 MB
  bf16_t* Vt  = (bf16_t*)(ws + 25690112);   // 8 MB  (total 32.5 MB)
  bf16_t* Yb  = Xln;                        // alias: Xln dead after QKV GEMM

  wtr_kernel<<<1024, 256, 0, stream>>>(Wq, Wk, Wv, Wp, Wt);
  ln_kernel<<<4096, 256, 0, stream>>>(x, gamma, beta, Xln);
  gemm_kernel<0><<<dim3(128, 6), 256, 0, stream>>>(
      Xln, Wt, bq, bk, bv, Qb, Kb, Vt, nullptr);
  attn_kernel<<<1024, 256, 0, stream>>>(Qb, Kb, Vt, Yb);
  gemm_kernel<1><<<dim3(128, 2), 256, 0, stream>>>(
      Yb, Wt + 3*65536, bp, nullptr, nullptr, nullptr, nullptr, nullptr, out);
}

// Round 7
// 78.284 us; speedup vs baseline: 2.7333x; 1.0145x over previous
//
#include <hip/hip_runtime.h>
#include <hip/hip_bf16.h>

typedef __bf16 bf16_t;
typedef __attribute__((ext_vector_type(8))) __bf16 bf16x8;
typedef __attribute__((ext_vector_type(4))) float f32x4;
typedef __attribute__((ext_vector_type(4))) short s16x4;

#define GLDS16(g, l) __builtin_amdgcn_global_load_lds( \
    (const __attribute__((address_space(1))) unsigned int*)(g), \
    (__attribute__((address_space(3))) unsigned int*)(l), 16, 0, 0)

__device__ __forceinline__ float fexp2(float x) {
#if __has_builtin(__builtin_amdgcn_exp2f)
  return __builtin_amdgcn_exp2f(x);
#else
  return exp2f(x);
#endif
}

// Q pre-scale: 1/sqrt(32) * log2(e) folded into QKV-GEMM epilogue; attention
// softmax runs in the exp2 domain (raw v_exp_f32, no per-score multiply).
#define QSCALE (0.17677669529663688f * 1.4426950408889634f)

// ---------------------------------------------------------------------------
// Kernel 1: convert Wq/Wk/Wv/Wp (f32 [256k][256n]) -> bf16 transposed [n][k]
// ---------------------------------------------------------------------------
__global__ __launch_bounds__(256) void wtr_kernel(
    const float* __restrict__ Wq, const float* __restrict__ Wk,
    const float* __restrict__ Wv, const float* __restrict__ Wp,
    bf16_t* __restrict__ Wt)
{
  const int idx = blockIdx.x * 256 + threadIdx.x;   // 0 .. 262143
  const int mat = idx >> 16;
  const int e   = idx & 65535;
  const int k   = e >> 8;
  const int n   = e & 255;
  const float* W = (mat == 0) ? Wq : (mat == 1) ? Wk : (mat == 2) ? Wv : Wp;
  Wt[(size_t)mat * 65536 + n * 256 + k] = (bf16_t)W[e];  // e == k*256+n
}

// ---------------------------------------------------------------------------
// Kernel 2: LayerNorm, f32 -> bf16. One wave per token (256 ch = 64 lanes x4).
// ---------------------------------------------------------------------------
__global__ __launch_bounds__(256) void ln_kernel(
    const float* __restrict__ x, const float* __restrict__ gamma,
    const float* __restrict__ beta, bf16_t* __restrict__ Xln)
{
  const int wave = threadIdx.x >> 6, lane = threadIdx.x & 63;
  const int tok = blockIdx.x * 4 + wave;
  const float4 v = *reinterpret_cast<const float4*>(x + (size_t)tok * 256 + lane * 4);
  float s1 = v.x + v.y + v.z + v.w;
  float s2 = v.x*v.x + v.y*v.y + v.z*v.z + v.w*v.w;
  #pragma unroll
  for (int off = 1; off < 64; off <<= 1) {
    s1 += __shfl_xor(s1, off);
    s2 += __shfl_xor(s2, off);
  }
  const float mean = s1 * (1.0f/256.0f);
  const float var  = s2 * (1.0f/256.0f) - mean*mean;
  const float rstd = rsqrtf(var + 1e-5f);
  const float4 g  = *reinterpret_cast<const float4*>(gamma + lane*4);
  const float4 be = *reinterpret_cast<const float4*>(beta  + lane*4);
  union { bf16_t h4[4]; unsigned long long u; } pk;
  pk.h4[0] = (bf16_t)((v.x-mean)*rstd*g.x + be.x);
  pk.h4[1] = (bf16_t)((v.y-mean)*rstd*g.y + be.y);
  pk.h4[2] = (bf16_t)((v.z-mean)*rstd*g.z + be.z);
  pk.h4[3] = (bf16_t)((v.w-mean)*rstd*g.w + be.w);
  *reinterpret_cast<unsigned long long*>(Xln + (size_t)tok*256 + lane*4) = pk.u;
}

// ---------------------------------------------------------------------------
// Kernel 3/5: bf16 MFMA GEMM, BM=128 BN=128 BK=64, 4 waves (2x2), K=256.
// MODE 0: A=Xln, B selects Wq/Wk/Wv by blockIdx.y; writes Qb (pre-scaled by
//         QSCALE) / Kb (token-major) or Vt (transposed [b][h][d][n]).
// MODE 1: A=Yb, B=Wpt; writes f32 out + bias.
// LDS tiles XOR-swizzled (byte ^= (row&7)<<4) via pre-swizzled global source.
// ---------------------------------------------------------------------------
template<int MODE>
__global__ __launch_bounds__(256) void gemm_kernel(
    const bf16_t* __restrict__ A, const bf16_t* __restrict__ Wt,
    const float* __restrict__ b0, const float* __restrict__ b1,
    const float* __restrict__ b2,
    bf16_t* __restrict__ Qb, bf16_t* __restrict__ Kb, bf16_t* __restrict__ Vt,
    float* __restrict__ Fout)
{
  __shared__ __align__(16) bf16_t As[128*64];
  __shared__ __align__(16) bf16_t Bs[128*64];
  const int tid  = threadIdx.x;
  const int lane = tid & 63, wave = tid >> 6;
  const int lg = lane >> 4, li = lane & 15;
  const int wm = wave >> 1, wn = wave & 1;
  const int mt = blockIdx.x;
  const int nt = blockIdx.y;
  int mat, nbase;
  const bf16_t* Bm;
  if (MODE == 0) { mat = nt >> 1; nbase = (nt & 1) * 128; Bm = Wt + (size_t)mat * 65536; }
  else           { mat = 3;       nbase = nt * 128;       Bm = Wt; }

  f32x4 acc[4][4] = {};

  for (int kt = 0; kt < 4; ++kt) {
    __syncthreads();
    #pragma unroll
    for (int i = 0; i < 4; ++i) {
      const int idx = i*256 + tid;
      const int row = idx >> 3, ck = idx & 7;
      const int cs = ck ^ (row & 7);
      GLDS16(A + (size_t)(mt*128 + row)*256 + kt*64 + cs*8, As + idx*8);
    }
    #pragma unroll
    for (int i = 0; i < 4; ++i) {
      const int idx = i*256 + tid;
      const int row = idx >> 3, ck = idx & 7;
      const int cs = ck ^ (row & 7);
      GLDS16(Bm + (size_t)(nbase + row)*256 + kt*64 + cs*8, Bs + idx*8);
    }
    __syncthreads();
    #pragma unroll
    for (int kk = 0; kk < 2; ++kk) {
      bf16x8 af[4], bfv[4];
      #pragma unroll
      for (int mi = 0; mi < 4; ++mi) {
        const int row = wm*64 + mi*16 + li;
        const int c = (kk*4 + lg) ^ (row & 7);
        af[mi] = *reinterpret_cast<const bf16x8*>(As + row*64 + c*8);
      }
      #pragma unroll
      for (int ni = 0; ni < 4; ++ni) {
        const int row = wn*64 + ni*16 + li;
        const int c = (kk*4 + lg) ^ (row & 7);
        bfv[ni] = *reinterpret_cast<const bf16x8*>(Bs + row*64 + c*8);
      }
      #pragma unroll
      for (int mi = 0; mi < 4; ++mi)
        #pragma unroll
        for (int ni = 0; ni < 4; ++ni)
          acc[mi][ni] = __builtin_amdgcn_mfma_f32_16x16x32_bf16(af[mi], bfv[ni], acc[mi][ni], 0, 0, 0);
    }
  }

  if (MODE == 0) {
    const float* bias = (mat == 0) ? b0 : (mat == 1) ? b1 : b2;
    if (mat < 2) {
      bf16_t* Out = (mat == 0) ? Qb : Kb;
      const float osc = (mat == 0) ? QSCALE : 1.0f;
      #pragma unroll
      for (int mi = 0; mi < 4; ++mi)
        #pragma unroll
        for (int ni = 0; ni < 4; ++ni) {
          const int col = nbase + wn*64 + ni*16 + li;
          const float bb = bias[col];
          #pragma unroll
          for (int r = 0; r < 4; ++r) {
            const int row = mt*128 + wm*64 + mi*16 + lg*4 + r;
            Out[(size_t)row*256 + col] = (bf16_t)((acc[mi][ni][r] + bb) * osc);
          }
        }
    } else {
      // V: write transposed Vt[b][h][d][n], 4 consecutive tokens -> 8B store
      #pragma unroll
      for (int mi = 0; mi < 4; ++mi)
        #pragma unroll
        for (int ni = 0; ni < 4; ++ni) {
          const int col = nbase + wn*64 + ni*16 + li;
          const int hh = col >> 5, dd = col & 31;
          const float bb = bias[col];
          const int row0 = mt*128 + wm*64 + mi*16 + lg*4;
          const int bi = row0 >> 10, nn = row0 & 1023;
          union { bf16_t h4[4]; unsigned long long u; } pk;
          #pragma unroll
          for (int r = 0; r < 4; ++r) pk.h4[r] = (bf16_t)(acc[mi][ni][r] + bb);
          *reinterpret_cast<unsigned long long*>(
              Vt + ((size_t)(bi*8 + hh)*32 + dd)*1024 + nn) = pk.u;
        }
    }
  } else {
    #pragma unroll
    for (int mi = 0; mi < 4; ++mi)
      #pragma unroll
      for (int ni = 0; ni < 4; ++ni) {
        const int col = nbase + wn*64 + ni*16 + li;
        const float bb = b0[col];
        #pragma unroll
        for (int r = 0; r < 4; ++r) {
          const int row = mt*128 + wm*64 + mi*16 + lg*4 + r;
          Fout[(size_t)row*256 + col] = acc[mi][ni][r] + bb;
        }
      }
  }
}

// ---------------------------------------------------------------------------
// Kernel 4: flash attention, LDS-staged K/V, 3-buffer counted-vmcnt pipeline.
// Block = (b,h, 128 q-rows), 4 waves x 32 q-rows (2 Q-fragments each).
// Per chunk: s_waitcnt vmcnt(2) (stage mc ready, stage mc+1 in flight) ->
// raw s_barrier -> issue stage(mc+2) -> compute. Never drains vmcnt to 0
// mid-loop (T3/T4); 3 buffers separate the write-after-read hazard by a
// full barrier interval.
// VALU cuts: row-sums via mfma(ones, P) on the MFMA pipe (replaces 32
// psum adds/lane/chunk + end shfl-reduce); exp2 skips the "-m" sub while
// un-bumped (defer-max, m==0 on the common path).
// ---------------------------------------------------------------------------
__global__ __launch_bounds__(256, 4) void attn_kernel(
    const bf16_t* __restrict__ Qb, const bf16_t* __restrict__ Kb,
    const bf16_t* __restrict__ Vt, bf16_t* __restrict__ Yb)
{
  __shared__ __align__(16) char Ks[3][4096];
  __shared__ __align__(16) char Vs[3][4096];
  const int tid  = threadIdx.x;
  const int wave = tid >> 6, lane = tid & 63;
  const int lg = lane >> 4, li = lane & 15;
  const int gid = blockIdx.x;
  const int qt = (gid >> 3) & 7;
  const int bh = ((gid >> 6) << 3) | (gid & 7);   // blocks of one bh: same XCD
  const int b  = bh >> 3, hh = bh & 7;
  const int tok0 = b*1024 + qt*128 + wave*32;

  // B-operand: Q^T[d][q]; lane holds q=li within each 16-row fragment
  const bf16x8 qf0 = *reinterpret_cast<const bf16x8*>(
      Qb + (size_t)(tok0 + li)*256 + hh*32 + lg*8);
  const bf16x8 qf1 = *reinterpret_cast<const bf16x8*>(
      Qb + (size_t)(tok0 + 16 + li)*256 + hh*32 + lg*8);

  // ---- staging sources (per-thread, inverse-swizzled) ----
  const int kt_ = tid >> 2, ks_ = tid & 3;     // K: thread -> (tok, 16B slot)
  const bf16_t* Ksrc = Kb + (size_t)(b*1024 + kt_)*256 + hh*32
                          + ((ks_ ^ ((kt_ >> 1) & 3)) * 8);
  const int vd_ = tid >> 3, vs_ = tid & 7;     // V: thread -> (d, 16B slot)
  const bf16_t* Vsrc = Vt + ((size_t)bh*32 + vd_)*1024
                          + ((vs_ ^ (vd_ & 7)) * 8);

  // ---- LDS read offsets (swizzled to match) ----
  const int kof = li*64 + ((lg ^ ((li >> 1) & 3)) * 16);   // + ct*1024
  int vof[4];
  #pragma unroll
  for (int ct = 0; ct < 4; ++ct)
    vof[ct] = li*128 + (((ct*2 + (lg >> 1)) ^ (li & 7)) * 16) + (lg & 1)*8;

  const f32x4 fz = {0.f, 0.f, 0.f, 0.f};
  f32x4 acc00 = fz, acc01 = fz;      // qf0 rows: d = lg*4+r (+16), q = li
  f32x4 acc10 = fz, acc11 = fz;      // qf1 rows
  f32x4 accl0 = fz, accl1 = fz;      // row-sum accumulators (ones-MFMA)
  float m0 = 0.f, m1 = 0.f;          // defer-max running max (log2 domain)
  bool bump0 = false, bump1 = false;

  const short oneb = 0x3F80;         // bf16 1.0
  const s16x4 vone = {oneb, oneb, oneb, oneb};

  // prologue: stage chunks 0 and 1 (4 outstanding vmem ops)
  GLDS16(Ksrc,         &Ks[0][tid*16]);
  GLDS16(Vsrc,         &Vs[0][tid*16]);
  GLDS16(Ksrc + 16384, &Ks[1][tid*16]);
  GLDS16(Vsrc + 64,    &Vs[1][tid*16]);

  #pragma unroll
  for (int mc = 0; mc < 16; ++mc) {
    // stage(mc) complete; stage(mc+1) stays in flight (counted wait, T4)
    if (mc < 15) asm volatile("s_waitcnt vmcnt(2)" ::: "memory");
    else         asm volatile("s_waitcnt vmcnt(0)" ::: "memory");
    __builtin_amdgcn_s_barrier();
    asm volatile("" ::: "memory");   // no LDS reads hoist above the barrier
    if (mc + 2 < 16) {
      GLDS16(Ksrc + (size_t)(mc+2)*16384, &Ks[(mc+2)%3][tid*16]);
      GLDS16(Vsrc + (mc+2)*64,            &Vs[(mc+2)%3][tid*16]);
    }
    const char* kb = &Ks[mc%3][0];
    const char* vb = &Vs[mc%3][0];
    // ---- QK^T from LDS K tile (one K-frag read feeds both Q-frags) ----
    f32x4 s0[4], s1[4];
    #pragma unroll
    for (int ct = 0; ct < 4; ++ct) {
      const bf16x8 kfrag = *reinterpret_cast<const bf16x8*>(kb + kof + ct*1024);
      s0[ct] = __builtin_amdgcn_mfma_f32_16x16x32_bf16(kfrag, qf0, fz, 0, 0, 0);
      s1[ct] = __builtin_amdgcn_mfma_f32_16x16x32_bf16(kfrag, qf1, fz, 0, 0, 0);
    }
    // ---- V quads from LDS V tile (shared by both Q-frags) ----
    s16x4 vq0[4], vq1[4];
    #pragma unroll
    for (int ct = 0; ct < 4; ++ct) {
      vq0[ct] = *reinterpret_cast<const s16x4*>(vb + vof[ct]);
      vq1[ct] = *reinterpret_cast<const s16x4*>(vb + vof[ct] + 16*128);
    }
    // ---- defer-max softmax, fragment 0 ----
    {
      float mxa = fmaxf(fmaxf(s0[0][0], s0[0][1]), fmaxf(s0[0][2], s0[0][3]));
      float mxb = fmaxf(fmaxf(s0[1][0], s0[1][1]), fmaxf(s0[1][2], s0[1][3]));
      float mxc = fmaxf(fmaxf(s0[2][0], s0[2][1]), fmaxf(s0[2][2], s0[2][3]));
      float mxd = fmaxf(fmaxf(s0[3][0], s0[3][1]), fmaxf(s0[3][2], s0[3][3]));
      const float pmax = fmaxf(fmaxf(mxa, mxb), fmaxf(mxc, mxd));
      if (!__all(pmax - m0 <= 8.0f)) {
        float rmx = fmaxf(pmax, __shfl_xor(pmax, 16));
        rmx = fmaxf(rmx, __shfl_xor(rmx, 32));
        const float mnew = fmaxf(m0, rmx);
        const float sf = fexp2(m0 - mnew);
        #pragma unroll
        for (int r = 0; r < 4; ++r) {
          acc00[r] *= sf; acc01[r] *= sf; accl0[r] *= sf;
        }
        m0 = mnew; bump0 = true;
      }
      if (!bump0) {
        #pragma unroll
        for (int ct = 0; ct < 4; ++ct)
          #pragma unroll
          for (int r = 0; r < 4; ++r) s0[ct][r] = fexp2(s0[ct][r]);
      } else {
        #pragma unroll
        for (int ct = 0; ct < 4; ++ct)
          #pragma unroll
          for (int r = 0; r < 4; ++r) s0[ct][r] = fexp2(s0[ct][r] - m0);
      }
    }
    // ---- defer-max softmax, fragment 1 ----
    {
      float mxa = fmaxf(fmaxf(s1[0][0], s1[0][1]), fmaxf(s1[0][2], s1[0][3]));
      float mxb = fmaxf(fmaxf(s1[1][0], s1[1][1]), fmaxf(s1[1][2], s1[1][3]));
      float mxc = fmaxf(fmaxf(s1[2][0], s1[2][1]), fmaxf(s1[2][2], s1[2][3]));
      float mxd = fmaxf(fmaxf(s1[3][0], s1[3][1]), fmaxf(s1[3][2], s1[3][3]));
      const float pmax = fmaxf(fmaxf(mxa, mxb), fmaxf(mxc, mxd));
      if (!__all(pmax - m1 <= 8.0f)) {
        float rmx = fmaxf(pmax, __shfl_xor(pmax, 16));
        rmx = fmaxf(rmx, __shfl_xor(rmx, 32));
        const float mnew = fmaxf(m1, rmx);
        const float sf = fexp2(m1 - mnew);
        #pragma unroll
        for (int r = 0; r < 4; ++r) {
          acc10[r] *= sf; acc11[r] *= sf; accl1[r] *= sf;
        }
        m1 = mnew; bump1 = true;
      }
      if (!bump1) {
        #pragma unroll
        for (int ct = 0; ct < 4; ++ct)
          #pragma unroll
          for (int r = 0; r < 4; ++r) s1[ct][r] = fexp2(s1[ct][r]);
      } else {
        #pragma unroll
        for (int ct = 0; ct < 4; ++ct)
          #pragma unroll
          for (int r = 0; r < 4; ++r) s1[ct][r] = fexp2(s1[ct][r] - m1);
      }
    }
    // ---- pack quads; PV + ones row-sum via 16x16x16 MFMA ----
    #pragma unroll
    for (int ct = 0; ct < 4; ++ct) {
      union { bf16_t h4[4]; s16x4 v; } p0, p1;
      #pragma unroll
      for (int r = 0; r < 4; ++r) { p0.h4[r] = (bf16_t)s0[ct][r];
                                    p1.h4[r] = (bf16_t)s1[ct][r]; }
      acc00 = __builtin_amdgcn_mfma_f32_16x16x16bf16_1k(vq0[ct], p0.v, acc00, 0, 0, 0);
      acc01 = __builtin_amdgcn_mfma_f32_16x16x16bf16_1k(vq1[ct], p0.v, acc01, 0, 0, 0);
      accl0 = __builtin_amdgcn_mfma_f32_16x16x16bf16_1k(vone,    p0.v, accl0, 0, 0, 0);
      acc10 = __builtin_amdgcn_mfma_f32_16x16x16bf16_1k(vq0[ct], p1.v, acc10, 0, 0, 0);
      acc11 = __builtin_amdgcn_mfma_f32_16x16x16bf16_1k(vq1[ct], p1.v, acc11, 0, 0, 0);
      accl1 = __builtin_amdgcn_mfma_f32_16x16x16bf16_1k(vone,    p1.v, accl1, 0, 0, 0);
    }
  }

  // l = ones-MFMA row sums (all rows identical; no cross-lane reduce needed)
  const float inv0 = 1.0f / accl0[0];
  const float inv1 = 1.0f / accl1[0];
  union { bf16_t h4[4]; unsigned long long u; } o00, o01, o10, o11;
  #pragma unroll
  for (int r = 0; r < 4; ++r) {
    o00.h4[r] = (bf16_t)(acc00[r]*inv0);
    o01.h4[r] = (bf16_t)(acc01[r]*inv0);
    o10.h4[r] = (bf16_t)(acc10[r]*inv1);
    o11.h4[r] = (bf16_t)(acc11[r]*inv1);
  }
  bf16_t* yp0 = Yb + (size_t)(tok0 + li)*256 + hh*32;
  bf16_t* yp1 = Yb + (size_t)(tok0 + 16 + li)*256 + hh*32;
  *reinterpret_cast<unsigned long long*>(yp0 + lg*4)      = o00.u;
  *reinterpret_cast<unsigned long long*>(yp0 + 16 + lg*4) = o01.u;
  *reinterpret_cast<unsigned long long*>(yp1 + lg*4)      = o10.u;
  *reinterpret_cast<unsigned long long*>(yp1 + 16 + lg*4) = o11.u;
}

// ---------------------------------------------------------------------------
extern "C" void kernel_launch(void* const* d_in, const int* in_sizes, int n_in,
                              void* d_out, int out_size, void* d_ws, size_t ws_size,
                              hipStream_t stream) {
  const float* x     = (const float*)d_in[0];
  const float* gamma = (const float*)d_in[1];
  const float* beta  = (const float*)d_in[2];
  const float* Wq    = (const float*)d_in[3];
  const float* bq    = (const float*)d_in[4];
  const float* Wk    = (const float*)d_in[5];
  const float* bk    = (const float*)d_in[6];
  const float* Wv    = (const float*)d_in[7];
  const float* bv    = (const float*)d_in[8];
  const float* Wp    = (const float*)d_in[9];
  const float* bp    = (const float*)d_in[10];
  float* out = (float*)d_out;

  char* ws = (char*)d_ws;
  bf16_t* Wt  = (bf16_t*)(ws);              // 4 * 65536 bf16 = 512 KB
  bf16_t* Xln = (bf16_t*)(ws + 524288);     // 16384*256 bf16 = 8 MB
  bf16_t* Qb  = (bf16_t*)(ws + 8912896);    // 8 MB
  bf16_t* Kb  = (bf16_t*)(ws + 17301504);   // 8 MB
  bf16_t* Vt  = (bf16_t*)(ws + 25690112);   // 8 MB  (total 32.5 MB)
  bf16_t* Yb  = Xln;                        // alias: Xln dead after QKV GEMM

  wtr_kernel<<<1024, 256, 0, stream>>>(Wq, Wk, Wv, Wp, Wt);
  ln_kernel<<<4096, 256, 0, stream>>>(x, gamma, beta, Xln);
  gemm_kernel<0><<<dim3(128, 6), 256, 0, stream>>>(
      Xln, Wt, bq, bk, bv, Qb, Kb, Vt, nullptr);
  attn_kernel<<<1024, 256, 0, stream>>>(Qb, Kb, Vt, Yb);
  gemm_kernel<1><<<dim3(128, 2), 256, 0, stream>>>(
      Yb, Wt + 3*65536, bp, nullptr, nullptr, nullptr, nullptr, nullptr, out);
}

// Round 8
// 72.032 us; speedup vs baseline: 2.9706x; 1.0868x over previous
//
#include <hip/hip_runtime.h>
#include <hip/hip_bf16.h>

typedef __bf16 bf16_t;
typedef __attribute__((ext_vector_type(8))) __bf16 bf16x8;
typedef __attribute__((ext_vector_type(4))) float f32x4;
typedef __attribute__((ext_vector_type(4))) short s16x4;

#define GLDS16(g, l) __builtin_amdgcn_global_load_lds( \
    (const __attribute__((address_space(1))) unsigned int*)(g), \
    (__attribute__((address_space(3))) unsigned int*)(l), 16, 0, 0)

__device__ __forceinline__ float fexp2(float x) {
#if __has_builtin(__builtin_amdgcn_exp2f)
  return __builtin_amdgcn_exp2f(x);
#else
  return exp2f(x);
#endif
}

// Q pre-scale: 1/sqrt(32) * log2(e) folded into QKV-GEMM epilogue; attention
// softmax runs in the exp2 domain (raw v_exp_f32, no per-score multiply).
#define QSCALE (0.17677669529663688f * 1.4426950408889634f)

// ---------------------------------------------------------------------------
// Kernel 1+2 merged: blocks [0,1024): weight convert/transpose f32->bf16;
// blocks [1024,5120): LayerNorm f32->bf16, one wave per token.
// ---------------------------------------------------------------------------
__global__ __launch_bounds__(256) void lnwtr_kernel(
    const float* __restrict__ x, const float* __restrict__ gamma,
    const float* __restrict__ beta, bf16_t* __restrict__ Xln,
    const float* __restrict__ Wq, const float* __restrict__ Wk,
    const float* __restrict__ Wv, const float* __restrict__ Wp,
    bf16_t* __restrict__ Wt)
{
  if (blockIdx.x < 1024) {
    const int idx = blockIdx.x * 256 + threadIdx.x;   // 0 .. 262143
    const int mat = idx >> 16;
    const int e   = idx & 65535;
    const int k   = e >> 8;
    const int n   = e & 255;
    const float* W = (mat == 0) ? Wq : (mat == 1) ? Wk : (mat == 2) ? Wv : Wp;
    Wt[(size_t)mat * 65536 + n * 256 + k] = (bf16_t)W[e];  // e == k*256+n
    return;
  }
  const int wave = threadIdx.x >> 6, lane = threadIdx.x & 63;
  const int tok = (blockIdx.x - 1024) * 4 + wave;
  const float4 v = *reinterpret_cast<const float4*>(x + (size_t)tok * 256 + lane * 4);
  float s1 = v.x + v.y + v.z + v.w;
  float s2 = v.x*v.x + v.y*v.y + v.z*v.z + v.w*v.w;
  #pragma unroll
  for (int off = 1; off < 64; off <<= 1) {
    s1 += __shfl_xor(s1, off);
    s2 += __shfl_xor(s2, off);
  }
  const float mean = s1 * (1.0f/256.0f);
  const float var  = s2 * (1.0f/256.0f) - mean*mean;
  const float rstd = rsqrtf(var + 1e-5f);
  const float4 g  = *reinterpret_cast<const float4*>(gamma + lane*4);
  const float4 be = *reinterpret_cast<const float4*>(beta  + lane*4);
  union { bf16_t h4[4]; unsigned long long u; } pk;
  pk.h4[0] = (bf16_t)((v.x-mean)*rstd*g.x + be.x);
  pk.h4[1] = (bf16_t)((v.y-mean)*rstd*g.y + be.y);
  pk.h4[2] = (bf16_t)((v.z-mean)*rstd*g.z + be.z);
  pk.h4[3] = (bf16_t)((v.w-mean)*rstd*g.w + be.w);
  *reinterpret_cast<unsigned long long*>(Xln + (size_t)tok*256 + lane*4) = pk.u;
}

// ---------------------------------------------------------------------------
// Kernel 3/5: bf16 MFMA GEMM, BM=128 BN=128 BK=64, 4 waves (2x2), K=256.
// MODE 0: A=Xln, B selects Wq/Wk/Wv by blockIdx.y; writes Qb (pre-scaled by
//         QSCALE) / Kb (token-major) or Vt (transposed [b][h][d][n]).
// MODE 1: A=Yb, B=Wpt; writes f32 out + bias.
// LDS tiles XOR-swizzled (byte ^= (row&7)<<4) via pre-swizzled global source.
// ---------------------------------------------------------------------------
template<int MODE>
__global__ __launch_bounds__(256) void gemm_kernel(
    const bf16_t* __restrict__ A, const bf16_t* __restrict__ Wt,
    const float* __restrict__ b0, const float* __restrict__ b1,
    const float* __restrict__ b2,
    bf16_t* __restrict__ Qb, bf16_t* __restrict__ Kb, bf16_t* __restrict__ Vt,
    float* __restrict__ Fout)
{
  __shared__ __align__(16) bf16_t As[128*64];
  __shared__ __align__(16) bf16_t Bs[128*64];
  const int tid  = threadIdx.x;
  const int lane = tid & 63, wave = tid >> 6;
  const int lg = lane >> 4, li = lane & 15;
  const int wm = wave >> 1, wn = wave & 1;
  const int mt = blockIdx.x;
  const int nt = blockIdx.y;
  int mat, nbase;
  const bf16_t* Bm;
  if (MODE == 0) { mat = nt >> 1; nbase = (nt & 1) * 128; Bm = Wt + (size_t)mat * 65536; }
  else           { mat = 3;       nbase = nt * 128;       Bm = Wt; }

  f32x4 acc[4][4] = {};

  for (int kt = 0; kt < 4; ++kt) {
    __syncthreads();
    #pragma unroll
    for (int i = 0; i < 4; ++i) {
      const int idx = i*256 + tid;
      const int row = idx >> 3, ck = idx & 7;
      const int cs = ck ^ (row & 7);
      GLDS16(A + (size_t)(mt*128 + row)*256 + kt*64 + cs*8, As + idx*8);
    }
    #pragma unroll
    for (int i = 0; i < 4; ++i) {
      const int idx = i*256 + tid;
      const int row = idx >> 3, ck = idx & 7;
      const int cs = ck ^ (row & 7);
      GLDS16(Bm + (size_t)(nbase + row)*256 + kt*64 + cs*8, Bs + idx*8);
    }
    __syncthreads();
    #pragma unroll
    for (int kk = 0; kk < 2; ++kk) {
      bf16x8 af[4], bfv[4];
      #pragma unroll
      for (int mi = 0; mi < 4; ++mi) {
        const int row = wm*64 + mi*16 + li;
        const int c = (kk*4 + lg) ^ (row & 7);
        af[mi] = *reinterpret_cast<const bf16x8*>(As + row*64 + c*8);
      }
      #pragma unroll
      for (int ni = 0; ni < 4; ++ni) {
        const int row = wn*64 + ni*16 + li;
        const int c = (kk*4 + lg) ^ (row & 7);
        bfv[ni] = *reinterpret_cast<const bf16x8*>(Bs + row*64 + c*8);
      }
      #pragma unroll
      for (int mi = 0; mi < 4; ++mi)
        #pragma unroll
        for (int ni = 0; ni < 4; ++ni)
          acc[mi][ni] = __builtin_amdgcn_mfma_f32_16x16x32_bf16(af[mi], bfv[ni], acc[mi][ni], 0, 0, 0);
    }
  }

  if (MODE == 0) {
    const float* bias = (mat == 0) ? b0 : (mat == 1) ? b1 : b2;
    if (mat < 2) {
      bf16_t* Out = (mat == 0) ? Qb : Kb;
      const float osc = (mat == 0) ? QSCALE : 1.0f;
      #pragma unroll
      for (int mi = 0; mi < 4; ++mi)
        #pragma unroll
        for (int ni = 0; ni < 4; ++ni) {
          const int col = nbase + wn*64 + ni*16 + li;
          const float bb = bias[col];
          #pragma unroll
          for (int r = 0; r < 4; ++r) {
            const int row = mt*128 + wm*64 + mi*16 + lg*4 + r;
            Out[(size_t)row*256 + col] = (bf16_t)((acc[mi][ni][r] + bb) * osc);
          }
        }
    } else {
      // V: write transposed Vt[b][h][d][n], 4 consecutive tokens -> 8B store
      #pragma unroll
      for (int mi = 0; mi < 4; ++mi)
        #pragma unroll
        for (int ni = 0; ni < 4; ++ni) {
          const int col = nbase + wn*64 + ni*16 + li;
          const int hh = col >> 5, dd = col & 31;
          const float bb = bias[col];
          const int row0 = mt*128 + wm*64 + mi*16 + lg*4;
          const int bi = row0 >> 10, nn = row0 & 1023;
          union { bf16_t h4[4]; unsigned long long u; } pk;
          #pragma unroll
          for (int r = 0; r < 4; ++r) pk.h4[r] = (bf16_t)(acc[mi][ni][r] + bb);
          *reinterpret_cast<unsigned long long*>(
              Vt + ((size_t)(bi*8 + hh)*32 + dd)*1024 + nn) = pk.u;
        }
    }
  } else {
    #pragma unroll
    for (int mi = 0; mi < 4; ++mi)
      #pragma unroll
      for (int ni = 0; ni < 4; ++ni) {
        const int col = nbase + wn*64 + ni*16 + li;
        const float bb = b0[col];
        #pragma unroll
        for (int r = 0; r < 4; ++r) {
          const int row = mt*128 + wm*64 + mi*16 + lg*4 + r;
          Fout[(size_t)row*256 + col] = acc[mi][ni][r] + bb;
        }
      }
  }
}

// ---------------------------------------------------------------------------
// Kernel 4: flash attention, 8 waves x 16 q-rows (512 threads), grid 1024
// -> 4 blocks/CU = 32 waves/CU target. __launch_bounds__(512,8) caps VGPR
// at 64 so 8 waves/SIMD are resident (occupancy was the round-7 limiter:
// VALU 59% busy, exp2-dominated).
// 3-buffer counted-vmcnt staging: each wave stages ONE 16B-slice per chunk
// (waves 0-3 cover K, 4-7 cover V); wave waits its own vmcnt(1) BEFORE the
// barrier, so the barrier publishes all slices. stage(mc+2) after the
// barrier writes buf[(mc+2)%3] - disjoint from bufs being read (WAR safe).
// Softmax per-lane (defer-max THR=8, branch-free common path), l via
// ones-MFMA, PV direct from QK output quads (16x16x16).
// ---------------------------------------------------------------------------
__global__ __launch_bounds__(512, 8) void attn_kernel(
    const bf16_t* __restrict__ Qb, const bf16_t* __restrict__ Kb,
    const bf16_t* __restrict__ Vt, bf16_t* __restrict__ Yb)
{
  __shared__ __align__(16) char Ks[3][4096];
  __shared__ __align__(16) char Vs[3][4096];
  const int tid  = threadIdx.x;
  const int wave = tid >> 6, lane = tid & 63;
  const int lg = lane >> 4, li = lane & 15;
  const int gid = blockIdx.x;
  const int qt = (gid >> 3) & 7;
  const int bh = ((gid >> 6) << 3) | (gid & 7);   // blocks of one bh: same XCD
  const int b  = bh >> 3, hh = bh & 7;
  const int tok0 = b*1024 + qt*128 + wave*16;

  // B-operand: Q^T[d][q]; lane holds q=li, d = lg*8..+7 (pre-scaled)
  const bf16x8 qf = *reinterpret_cast<const bf16x8*>(
      Qb + (size_t)(tok0 + li)*256 + hh*32 + lg*8);

  // ---- per-thread staging source (one 16B slice; waves 0-3 K, 4-7 V) ----
  const bf16_t* Ssrc;
  if (tid < 256) {
    const int s = tid, ktok = s >> 2, ks = s & 3;
    Ssrc = Kb + (size_t)(b*1024 + ktok)*256 + hh*32 + ((ks ^ ((ktok >> 1) & 3)) * 8);
  } else {
    const int s = tid - 256, vd = s >> 3, vs = s & 7;
    Ssrc = Vt + ((size_t)bh*32 + vd)*1024 + ((vs ^ (vd & 7)) * 8);
  }
  // chunk strides: K advances 64 tokens*256, V advances 64 tokens
  const size_t sstride = (tid < 256) ? (size_t)16384 : (size_t)64;
  const int sloff = (tid < 256) ? tid*16 : (tid-256)*16;
  char* sbase = (tid < 256) ? &Ks[0][0] : &Vs[0][0];

  // ---- LDS read offsets (swizzled to match staging) ----
  const int kof = li*64 + ((lg ^ ((li >> 1) & 3)) * 16);   // + ct*1024
  int vof[4];
  #pragma unroll
  for (int ct = 0; ct < 4; ++ct)
    vof[ct] = li*128 + (((ct*2 + (lg >> 1)) ^ (li & 7)) * 16) + (lg & 1)*8;

  const f32x4 fz = {0.f, 0.f, 0.f, 0.f};
  f32x4 acc0 = fz, acc1 = fz;        // Y^T: d = lg*4+r (+16), q = li
  f32x4 accl = fz;                   // row-sum accumulator (ones-MFMA)
  float m = 0.f;                     // defer-max running max (log2 domain)
  bool bump = false;

  const short oneb = 0x3F80;         // bf16 1.0
  const s16x4 vone = {oneb, oneb, oneb, oneb};

  // prologue: stage own slices for chunks 0 and 1 (2 outstanding/wave)
  GLDS16(Ssrc,           sbase + sloff);
  GLDS16(Ssrc + sstride, sbase + 4096 + sloff);

  #pragma unroll
  for (int mc = 0; mc < 16; ++mc) {
    // my slice for chunk mc landed; slice mc+1 stays in flight (T4)
    if (mc < 15) asm volatile("s_waitcnt vmcnt(1)" ::: "memory");
    else         asm volatile("s_waitcnt vmcnt(0)" ::: "memory");
    __builtin_amdgcn_s_barrier();    // publishes every wave's slice
    asm volatile("" ::: "memory");   // no LDS reads hoist above the barrier
    if (mc + 2 < 16)
      GLDS16(Ssrc + (size_t)(mc+2)*sstride, sbase + ((mc+2)%3)*4096 + sloff);
    const char* kb = &Ks[mc%3][0];
    const char* vb = &Vs[mc%3][0];
    // ---- QK^T from LDS K tile ----
    f32x4 s[4];
    #pragma unroll
    for (int ct = 0; ct < 4; ++ct) {
      const bf16x8 kfrag = *reinterpret_cast<const bf16x8*>(kb + kof + ct*1024);
      s[ct] = __builtin_amdgcn_mfma_f32_16x16x32_bf16(kfrag, qf, fz, 0, 0, 0);
    }
    // ---- defer-max check (max3-friendly tree) ----
    const float mxa = fmaxf(fmaxf(s[0][0], s[0][1]), fmaxf(s[0][2], s[0][3]));
    const float mxb = fmaxf(fmaxf(s[1][0], s[1][1]), fmaxf(s[1][2], s[1][3]));
    const float mxc = fmaxf(fmaxf(s[2][0], s[2][1]), fmaxf(s[2][2], s[2][3]));
    const float mxd = fmaxf(fmaxf(s[3][0], s[3][1]), fmaxf(s[3][2], s[3][3]));
    const float pmax = fmaxf(fmaxf(mxa, mxb), fmaxf(mxc, mxd));
    if (!__all(pmax - m <= 8.0f)) {
      float rmx = fmaxf(pmax, __shfl_xor(pmax, 16));
      rmx = fmaxf(rmx, __shfl_xor(rmx, 32));
      const float mnew = fmaxf(m, rmx);
      const float sf = fexp2(m - mnew);
      #pragma unroll
      for (int r = 0; r < 4; ++r) { acc0[r] *= sf; acc1[r] *= sf; accl[r] *= sf; }
      m = mnew; bump = true;
    }
    // ---- per-quad: exp2 -> pack -> PV (s[ct] dies early; low reg peak) ----
    #pragma unroll
    for (int ct = 0; ct < 4; ++ct) {
      union { bf16_t h4[4]; s16x4 v; } pk;
      if (!bump) {
        #pragma unroll
        for (int r = 0; r < 4; ++r) pk.h4[r] = (bf16_t)fexp2(s[ct][r]);
      } else {
        #pragma unroll
        for (int r = 0; r < 4; ++r) pk.h4[r] = (bf16_t)fexp2(s[ct][r] - m);
      }
      const s16x4 vq0 = *reinterpret_cast<const s16x4*>(vb + vof[ct]);
      const s16x4 vq1 = *reinterpret_cast<const s16x4*>(vb + vof[ct] + 16*128);
      acc0 = __builtin_amdgcn_mfma_f32_16x16x16bf16_1k(vq0,  pk.v, acc0, 0, 0, 0);
      acc1 = __builtin_amdgcn_mfma_f32_16x16x16bf16_1k(vq1,  pk.v, acc1, 0, 0, 0);
      accl = __builtin_amdgcn_mfma_f32_16x16x16bf16_1k(vone, pk.v, accl, 0, 0, 0);
    }
  }

  // l = ones-MFMA row sums (all rows identical; no cross-lane reduce)
  const float inv = 1.0f / accl[0];
  union { bf16_t h4[4]; unsigned long long u; } o0, o1;
  #pragma unroll
  for (int r = 0; r < 4; ++r) {
    o0.h4[r] = (bf16_t)(acc0[r]*inv);
    o1.h4[r] = (bf16_t)(acc1[r]*inv);
  }
  bf16_t* yp = Yb + (size_t)(tok0 + li)*256 + hh*32;
  *reinterpret_cast<unsigned long long*>(yp + lg*4)      = o0.u;
  *reinterpret_cast<unsigned long long*>(yp + 16 + lg*4) = o1.u;
}

// ---------------------------------------------------------------------------
extern "C" void kernel_launch(void* const* d_in, const int* in_sizes, int n_in,
                              void* d_out, int out_size, void* d_ws, size_t ws_size,
                              hipStream_t stream) {
  const float* x     = (const float*)d_in[0];
  const float* gamma = (const float*)d_in[1];
  const float* beta  = (const float*)d_in[2];
  const float* Wq    = (const float*)d_in[3];
  const float* bq    = (const float*)d_in[4];
  const float* Wk    = (const float*)d_in[5];
  const float* bk    = (const float*)d_in[6];
  const float* Wv    = (const float*)d_in[7];
  const float* bv    = (const float*)d_in[8];
  const float* Wp    = (const float*)d_in[9];
  const float* bp    = (const float*)d_in[10];
  float* out = (float*)d_out;

  char* ws = (char*)d_ws;
  bf16_t* Wt  = (bf16_t*)(ws);              // 4 * 65536 bf16 = 512 KB
  bf16_t* Xln = (bf16_t*)(ws + 524288);     // 16384*256 bf16 = 8 MB
  bf16_t* Qb  = (bf16_t*)(ws + 8912896);    // 8 MB
  bf16_t* Kb  = (bf16_t*)(ws + 17301504);   // 8 MB
  bf16_t* Vt  = (bf16_t*)(ws + 25690112);   // 8 MB  (total 32.5 MB)
  bf16_t* Yb  = Xln;                        // alias: Xln dead after QKV GEMM

  lnwtr_kernel<<<5120, 256, 0, stream>>>(x, gamma, beta, Xln,
                                         Wq, Wk, Wv, Wp, Wt);
  gemm_kernel<0><<<dim3(128, 6), 256, 0, stream>>>(
      Xln, Wt, bq, bk, bv, Qb, Kb, Vt, nullptr);
  attn_kernel<<<1024, 512, 0, stream>>>(Qb, Kb, Vt, Yb);
  gemm_kernel<1><<<dim3(128, 2), 256, 0, stream>>>(
      Yb, Wt + 3*65536, bp, nullptr, nullptr, nullptr, nullptr, nullptr, out);
}